// Round 1
// baseline (2278.864 us; speedup 1.0000x reference)
//
#include <hip/hip_runtime.h>
#include <stdint.h>
#include <math.h>

#define BB 32
#define TT 2048
#define CC 768
#define NTOK (BB*TT)                     // 65536
#define NTOT 50331648LL                  // BB*TT*CC
#define RANK0 25165823ULL                // NTOT/2 - 1
#define RANK1 25165824ULL                // NTOT/2

// ---- monotone float<->uint mapping (order-preserving) ----
__device__ inline unsigned int f2key(float f) {
    unsigned int u = __float_as_uint(f);
    return (u & 0x80000000u) ? ~u : (u | 0x80000000u);
}
__device__ inline float key2f(unsigned int k) {
    unsigned int u = (k & 0x80000000u) ? (k ^ 0x80000000u) : ~k;
    return __uint_as_float(u);
}

// ============ K1: per-token min/max/range + partial double sums ============
__global__ __launch_bounds__(256) void k_token_stats(
    const float* __restrict__ x, float* __restrict__ tokmin, float* __restrict__ tokmax,
    float* __restrict__ eulg, double* __restrict__ psum, double* __restrict__ psumsq,
    unsigned int* __restrict__ scal /* [0]=gmin_key [1]=gmax_key */)
{
    int token = blockIdx.x;
    int tid = threadIdx.x;
    const float* xp = x + (size_t)token * CC;
    float v0 = xp[tid], v1 = xp[tid + 256], v2 = xp[tid + 512];
    float mn = fminf(fminf(v0, v1), v2);
    float mx = fmaxf(fmaxf(v0, v1), v2);
    double s  = (double)v0 + (double)v1 + (double)v2;
    double ss = (double)v0 * (double)v0 + (double)v1 * (double)v1 + (double)v2 * (double)v2;
    __shared__ float smn[256], smx[256];
    __shared__ double sds[256], sdq[256];
    smn[tid] = mn; smx[tid] = mx; sds[tid] = s; sdq[tid] = ss;
    __syncthreads();
    for (int st = 128; st > 0; st >>= 1) {
        if (tid < st) {
            smn[tid] = fminf(smn[tid], smn[tid + st]);
            smx[tid] = fmaxf(smx[tid], smx[tid + st]);
            sds[tid] += sds[tid + st];
            sdq[tid] += sdq[tid + st];
        }
        __syncthreads();
    }
    if (tid == 0) {
        float bmn = smn[0], bmx = smx[0];
        tokmin[token] = bmn; tokmax[token] = bmx;
        float e = __fsub_rn(bmx, bmn);
        if ((token & (TT - 1)) == 0) e = __fmul_rn(e, 1e8f);
        eulg[token] = e;
        psum[token] = sds[0]; psumsq[token] = sdq[0];
        atomicMin(&scal[0], f2key(bmn));
        atomicMax(&scal[1], f2key(bmx));
    }
}

// ============ deterministic tree reduce for double partials ============
__global__ __launch_bounds__(256) void k_reduce256(
    const double* __restrict__ in1, const double* __restrict__ in2,
    double* __restrict__ out1, double* __restrict__ out2)
{
    __shared__ double a[256], b[256];
    int i = blockIdx.x * 256 + threadIdx.x;
    a[threadIdx.x] = in1[i]; b[threadIdx.x] = in2[i];
    __syncthreads();
    for (int st = 128; st > 0; st >>= 1) {
        if (threadIdx.x < st) { a[threadIdx.x] += a[threadIdx.x + st]; b[threadIdx.x] += b[threadIdx.x + st]; }
        __syncthreads();
    }
    if (threadIdx.x == 0) { out1[blockIdx.x] = a[0]; out2[blockIdx.x] = b[0]; }
}

// ============ radix-select pass A: top 11 bits ============
__global__ __launch_bounds__(256) void k_hist_top(const float4* __restrict__ x4,
                                                  unsigned int* __restrict__ hist1)
{
    __shared__ unsigned int h[2048];
    for (int i = threadIdx.x; i < 2048; i += 256) h[i] = 0;
    __syncthreads();
    const long long n4 = NTOT / 4;
    for (long long i = (long long)blockIdx.x * 256 + threadIdx.x; i < n4;
         i += (long long)gridDim.x * 256) {
        float4 v = x4[i];
        atomicAdd(&h[f2key(v.x) >> 21], 1u);
        atomicAdd(&h[f2key(v.y) >> 21], 1u);
        atomicAdd(&h[f2key(v.z) >> 21], 1u);
        atomicAdd(&h[f2key(v.w) >> 21], 1u);
    }
    __syncthreads();
    for (int i = threadIdx.x; i < 2048; i += 256) {
        unsigned int c = h[i];
        if (c) atomicAdd(&hist1[i], c);
    }
}

// scal layout (u32 at ws+16): [0]=gmin [1]=gmax [2..3]=b1 [4..5]=prefix [6..7]=b2 [8..9]=finkey
__global__ void k_sel1(unsigned int* __restrict__ scal, const unsigned int* __restrict__ hist1)
{
    if (threadIdx.x != 0) return;
    const unsigned long long ranks[2] = {RANK0, RANK1};
    for (int r = 0; r < 2; ++r) {
        unsigned long long k = ranks[r], c = 0; int b = 0;
        for (; b < 2048; ++b) { unsigned int hh = hist1[b]; if (k < c + hh) break; c += hh; }
        scal[2 + r] = (unsigned int)b;
        scal[4 + r] = (unsigned int)c;
    }
}

// ============ radix-select pass B: middle 11 bits ============
__global__ __launch_bounds__(256) void k_hist_mid(const float4* __restrict__ x4,
    const unsigned int* __restrict__ scal, unsigned int* __restrict__ hist2)
{
    __shared__ unsigned int h[2][2048];
    for (int i = threadIdx.x; i < 4096; i += 256) ((unsigned int*)h)[i] = 0;
    __syncthreads();
    const unsigned int t0 = scal[2], t1 = scal[3];
    const long long n4 = NTOT / 4;
    for (long long i = (long long)blockIdx.x * 256 + threadIdx.x; i < n4;
         i += (long long)gridDim.x * 256) {
        float4 v = x4[i];
        #pragma unroll
        for (int c = 0; c < 4; ++c) {
            float f = (c == 0) ? v.x : (c == 1) ? v.y : (c == 2) ? v.z : v.w;
            unsigned int k = f2key(f);
            unsigned int top = k >> 21, mid = (k >> 10) & 2047u;
            if (top == t0) atomicAdd(&h[0][mid], 1u);
            if (top == t1) atomicAdd(&h[1][mid], 1u);
        }
    }
    __syncthreads();
    for (int i = threadIdx.x; i < 2048; i += 256) {
        unsigned int c0 = h[0][i], c1 = h[1][i];
        if (c0) atomicAdd(&hist2[i], c0);
        if (c1) atomicAdd(&hist2[2048 + i], c1);
    }
}

__global__ void k_sel2(unsigned int* __restrict__ scal, const unsigned int* __restrict__ hist2)
{
    if (threadIdx.x != 0) return;
    const unsigned long long ranks[2] = {RANK0, RANK1};
    for (int r = 0; r < 2; ++r) {
        unsigned long long k = ranks[r] - (unsigned long long)scal[4 + r];
        unsigned long long c = 0; int b = 0;
        for (; b < 2048; ++b) { unsigned int hh = hist2[r * 2048 + b]; if (k < c + hh) break; c += hh; }
        scal[6 + r] = (unsigned int)b;
        scal[4 + r] = scal[4 + r] + (unsigned int)c;
    }
}

// ============ radix-select pass C: low 10 bits ============
__global__ __launch_bounds__(256) void k_hist_low(const float4* __restrict__ x4,
    const unsigned int* __restrict__ scal, unsigned int* __restrict__ hist3)
{
    __shared__ unsigned int h[2][1024];
    for (int i = threadIdx.x; i < 2048; i += 256) ((unsigned int*)h)[i] = 0;
    __syncthreads();
    const unsigned int t22_0 = (scal[2] << 11) | scal[6];
    const unsigned int t22_1 = (scal[3] << 11) | scal[7];
    const long long n4 = NTOT / 4;
    for (long long i = (long long)blockIdx.x * 256 + threadIdx.x; i < n4;
         i += (long long)gridDim.x * 256) {
        float4 v = x4[i];
        #pragma unroll
        for (int c = 0; c < 4; ++c) {
            float f = (c == 0) ? v.x : (c == 1) ? v.y : (c == 2) ? v.z : v.w;
            unsigned int k = f2key(f);
            unsigned int top22 = k >> 10, low = k & 1023u;
            if (top22 == t22_0) atomicAdd(&h[0][low], 1u);
            if (top22 == t22_1) atomicAdd(&h[1][low], 1u);
        }
    }
    __syncthreads();
    for (int i = threadIdx.x; i < 1024; i += 256) {
        unsigned int c0 = h[0][i], c1 = h[1][i];
        if (c0) atomicAdd(&hist3[i], c0);
        if (c1) atomicAdd(&hist3[1024 + i], c1);
    }
}

__global__ void k_sel3(unsigned int* __restrict__ scal, float* __restrict__ fscal,
                       const unsigned int* __restrict__ hist3, const double* __restrict__ gsum)
{
    if (threadIdx.x != 0) return;
    const unsigned long long ranks[2] = {RANK0, RANK1};
    for (int r = 0; r < 2; ++r) {
        unsigned long long k = ranks[r] - (unsigned long long)scal[4 + r];
        unsigned long long c = 0; int b = 0;
        for (; b < 1024; ++b) { unsigned int hh = hist3[r * 1024 + b]; if (k < c + hh) break; c += hh; }
        scal[8 + r] = (scal[2 + r] << 21) | (scal[6 + r] << 10) | (unsigned int)b;
    }
    float v0 = key2f(scal[8]), v1 = key2f(scal[9]);
    float mean = __fmul_rn(__fadd_rn(v0, v1), 0.5f);     // (a+b)/2 in f32
    double s = gsum[0], ss = gsum[1];
    const double NN = (double)NTOT;
    double var = (ss - s * s / NN) / (NN - 1.0);
    if (var < 0.0) var = 0.0;
    float stdf = (float)sqrt(var);
    float rng = __fsub_rn(key2f(scal[1]), key2f(scal[0]));
    float coeff = __fdiv_rn(stdf, rng);
    fscal[0] = mean; fscal[1] = stdf; fscal[2] = coeff;
}

// ============ K2: per-token band counts -> attn_std ============
__global__ __launch_bounds__(256) void k_count(const float* __restrict__ x,
    const float* __restrict__ eulg, const float* __restrict__ fscal, float* __restrict__ attn)
{
    int token = blockIdx.x, tid = threadIdx.x;
    float mean = fscal[0], coeff = fscal[2];
    float band = __fmul_rn(__fmul_rn(eulg[token], coeff), 0.8f);
    float hi = __fadd_rn(mean, band);
    float lo = __fsub_rn(mean, band);
    const float* xp = x + (size_t)token * CC;
    float v0 = xp[tid], v1 = xp[tid + 256], v2 = xp[tid + 512];
    int chi = (v0 < hi) + (v1 < hi) + (v2 < hi);
    int clo = (v0 < lo) + (v1 < lo) + (v2 < lo);
    __shared__ int sc[256];
    sc[tid] = (chi << 16) + clo;
    __syncthreads();
    for (int st = 128; st > 0; st >>= 1) {
        if (tid < st) sc[tid] += sc[tid + st];
        __syncthreads();
    }
    if (tid == 0) {
        int tot = sc[0];
        int d = (tot >> 16) - (tot & 0xffff);
        float a = fmaxf((float)d, 76.8f);                 // clip(.., COCO*C)
        float inv = __fdiv_rn(1.0f, a);
        attn[token] = (inv > 1.0f) ? 0.0f : inv;
    }
}

// ============ K3: per-batch stable sort + score + rank -> levels ============
__device__ inline void bitonic_sort(unsigned long long* keys, int tid) {
    for (int k = 2; k <= TT; k <<= 1) {
        for (int j = k >> 1; j > 0; j >>= 1) {
            __syncthreads();
            for (int i = tid; i < TT; i += 512) {
                int l = i ^ j;
                if (l > i) {
                    unsigned long long a = keys[i], c = keys[l];
                    bool up = ((i & k) == 0);
                    if (up ? (a > c) : (a < c)) { keys[i] = c; keys[l] = a; }
                }
            }
        }
    }
    __syncthreads();
}

__global__ __launch_bounds__(512) void k_sort(const float* __restrict__ eulg,
    const float* __restrict__ attn, const float* __restrict__ fscal,
    unsigned int* __restrict__ nlev)
{
    int b = blockIdx.x, tid = threadIdx.x;
    __shared__ unsigned long long keys[TT];
    __shared__ float av[TT];
    __shared__ int firstNeg;
    __shared__ int s_diff;
    const float stdf = fscal[1];
    const float THR = (float)(1.0 + 511.0 / 254.0);   // THRESHOLD in f32

    for (int t = tid; t < TT; t += 512) {
        float v = eulg[b * TT + t];
        keys[t] = ((unsigned long long)f2key(v) << 32) | (unsigned int)t;  // (value asc, idx asc)
    }
    if (tid == 0) firstNeg = TT;
    __syncthreads();
    bitonic_sort(keys, tid);

    for (int t = tid; t < TT; t += 512)
        av[t] = attn[b * TT + (unsigned int)(keys[t] & 0xffffffffu)];
    __syncthreads();

    for (int i = tid; i < TT; i += 512) {
        float vi = key2f((unsigned int)(keys[i] >> 32));
        float vd = key2f((unsigned int)(keys[TT - 1 - i] >> 32));
        float a  = __fmul_rn(vd, av[TT - 1 - i]);
        float bb = __fmul_rn(__fmul_rn(vi, av[i]), THR);
        float sc = __fdiv_rn(__fsub_rn(a, bb), stdf);
        if (sc < 0.0f) atomicMin(&firstNeg, i);
    }
    __syncthreads();
    if (tid == 0) {
        int mi = (firstNeg >= TT) ? 0 : firstNeg;       // argmax(all False) = 0
        s_diff = (mi - 1 > 0) ? (mi - 1) : 0;
    }
    __syncthreads();
    int diffv = s_diff;

    // second sort: (value desc, idx asc) -> reference-stable descending ranks
    for (int t = tid; t < TT; t += 512) {
        float v = eulg[b * TT + t];
        keys[t] = ((unsigned long long)(unsigned int)(~f2key(v)) << 32) | (unsigned int)t;
    }
    __syncthreads();
    bitonic_sort(keys, tid);

    for (int q = tid; q < TT; q += 512) {
        unsigned int token = (unsigned int)(keys[q] & 0xffffffffu);
        int rank = q;
        unsigned int levels = (rank > TT - 2 - diffv) ? 128u
                            : ((rank <= diffv) ? 512u : 256u);
        nlev[b * TT + token] = levels;
    }
}

// ============ K4: quantize / dequantize ============
__global__ __launch_bounds__(256) void k_quant(const float* __restrict__ x,
    const float* __restrict__ tokmin, const float* __restrict__ tokmax,
    const unsigned int* __restrict__ nlev, float* __restrict__ out)
{
    int token = blockIdx.x, tid = threadIdx.x;
    float mn = tokmin[token], mx = tokmax[token];
    float delta = fmaxf(__fdiv_rn(__fsub_rn(mx, mn), 255.0f), 1e-8f);
    float zp = rintf(__fdiv_rn(-mn, delta));              // round half-even == jnp.round
    float nlm1 = (float)(nlev[token] - 1u);
    const float* xp = x + (size_t)token * CC;
    float* op = out + (size_t)token * CC;
    #pragma unroll
    for (int k = 0; k < 3; ++k) {
        int idx = tid + k * 256;
        float v = xp[idx];
        float xi = __fadd_rn(rintf(__fdiv_rn(v, delta)), zp);
        float t = __fdiv_rn(xi, nlm1);
        t = fminf(fmaxf(t, 0.0f), 1.0f);
        float xq = __fmul_rn(t, nlm1);
        op[idx] = __fmul_rn(__fsub_rn(xq, zp), delta);
    }
}

extern "C" void kernel_launch(void* const* d_in, const int* in_sizes, int n_in,
                              void* d_out, int out_size, void* d_ws, size_t ws_size,
                              hipStream_t stream)
{
    (void)in_sizes; (void)n_in; (void)out_size; (void)ws_size;
    const float* x = (const float*)d_in[0];
    float* out = (float*)d_out;
    char* ws = (char*)d_ws;

    double* g_sum = (double*)ws;                           // [0]=sum [1]=sumsq
    unsigned int* scal = (unsigned int*)(ws + 16);         // 12 u32 slots
    float* fscal = (float*)(ws + 56);                      // mean,std,coeff
    unsigned int* hist1 = (unsigned int*)(ws + 128);       // 2048
    unsigned int* hist2 = (unsigned int*)(ws + 8320);      // 2*2048
    unsigned int* hist3 = (unsigned int*)(ws + 24704);     // 2*1024
    float* tokmin = (float*)(ws + 40960);
    float* tokmax = tokmin + NTOK;
    float* eulg   = tokmax + NTOK;
    float* attn   = eulg + NTOK;
    unsigned int* nlev = (unsigned int*)(attn + NTOK);
    double* psum   = (double*)(ws + 1351680);
    double* psumsq = psum + NTOK;
    double* p2sum  = psumsq + NTOK;
    double* p2sumsq = p2sum + 256;

    // zero scalars + histograms; init gmin key to 0xFFFFFFFF
    hipMemsetAsync(ws, 0, 32896, stream);
    hipMemsetAsync(ws + 16, 0xFF, 4, stream);

    k_token_stats<<<NTOK, 256, 0, stream>>>(x, tokmin, tokmax, eulg, psum, psumsq, scal);
    k_reduce256<<<256, 256, 0, stream>>>(psum, psumsq, p2sum, p2sumsq);
    k_reduce256<<<1, 256, 0, stream>>>(p2sum, p2sumsq, &g_sum[0], &g_sum[1]);
    k_hist_top<<<512, 256, 0, stream>>>((const float4*)x, hist1);
    k_sel1<<<1, 64, 0, stream>>>(scal, hist1);
    k_hist_mid<<<512, 256, 0, stream>>>((const float4*)x, scal, hist2);
    k_sel2<<<1, 64, 0, stream>>>(scal, hist2);
    k_hist_low<<<512, 256, 0, stream>>>((const float4*)x, scal, hist3);
    k_sel3<<<1, 64, 0, stream>>>(scal, fscal, hist3, g_sum);
    k_count<<<NTOK, 256, 0, stream>>>(x, eulg, fscal, attn);
    k_sort<<<BB, 512, 0, stream>>>(eulg, attn, fscal, nlev);
    k_quant<<<NTOK, 256, 0, stream>>>(x, tokmin, tokmax, nlev, out);
}

// Round 2
// 756.277 us; speedup vs baseline: 3.0133x; 3.0133x over previous
//
#include <hip/hip_runtime.h>
#include <stdint.h>
#include <math.h>

#define BB 32
#define TT 2048
#define CC 768
#define NTOK (BB*TT)                     // 65536
#define NTOT 50331648LL                  // BB*TT*CC
#define RANK0 25165823ULL                // NTOT/2 - 1
#define RANK1 25165824ULL                // NTOT/2

// ---- monotone float<->uint mapping (order-preserving) ----
__device__ inline unsigned int f2key(float f) {
    unsigned int u = __float_as_uint(f);
    return (u & 0x80000000u) ? ~u : (u | 0x80000000u);
}
__device__ inline float key2f(unsigned int k) {
    unsigned int u = (k & 0x80000000u) ? (k ^ 0x80000000u) : ~k;
    return __uint_as_float(u);
}

// ============ K1: wave-per-token stats + fused top-11 histogram ============
// block = 256 = 4 waves; each wave owns one token per iteration (768 floats =
// 192 float4 = 64 lanes x 3 float4). No global atomics except the LDS-hist
// flush (2048 spread addresses per block).
__global__ __launch_bounds__(256) void k_token_stats(
    const float4* __restrict__ x4, float* __restrict__ tokmin,
    float* __restrict__ tokmax, float* __restrict__ eulg,
    double* __restrict__ psum, double* __restrict__ psumsq,
    unsigned int* __restrict__ hist1)
{
    __shared__ unsigned int h[2048 * 4];          // 4 sub-hists by (tid&3)
    for (int i = threadIdx.x; i < 8192; i += 256) h[i] = 0;
    __syncthreads();
    const int wave = threadIdx.x >> 6, lane = threadIdx.x & 63;
    const int sub = threadIdx.x & 3;

    for (int token = blockIdx.x * 4 + wave; token < NTOK; token += gridDim.x * 4) {
        const float4* xp = x4 + (size_t)token * 192;
        float mn = INFINITY, mx = -INFINITY;
        double s = 0.0, ss = 0.0;
        #pragma unroll
        for (int k = 0; k < 3; ++k) {
            float4 v = xp[lane + k * 64];
            mn = fminf(mn, fminf(fminf(v.x, v.y), fminf(v.z, v.w)));
            mx = fmaxf(mx, fmaxf(fmaxf(v.x, v.y), fmaxf(v.z, v.w)));
            s  += (double)v.x + (double)v.y + (double)v.z + (double)v.w;
            ss += (double)v.x * (double)v.x + (double)v.y * (double)v.y
                + (double)v.z * (double)v.z + (double)v.w * (double)v.w;
            atomicAdd(&h[((f2key(v.x) >> 21) << 2) + sub], 1u);
            atomicAdd(&h[((f2key(v.y) >> 21) << 2) + sub], 1u);
            atomicAdd(&h[((f2key(v.z) >> 21) << 2) + sub], 1u);
            atomicAdd(&h[((f2key(v.w) >> 21) << 2) + sub], 1u);
        }
        #pragma unroll
        for (int d = 1; d < 64; d <<= 1) {
            mn = fminf(mn, __shfl_xor(mn, d));
            mx = fmaxf(mx, __shfl_xor(mx, d));
            s  += __shfl_xor(s, d);
            ss += __shfl_xor(ss, d);
        }
        if (lane == 0) {
            tokmin[token] = mn; tokmax[token] = mx;
            float e = __fsub_rn(mx, mn);
            if ((token & (TT - 1)) == 0) e = __fmul_rn(e, 1e8f);
            eulg[token] = e;
            psum[token] = s; psumsq[token] = ss;
        }
    }
    __syncthreads();
    for (int i = threadIdx.x; i < 2048; i += 256) {
        unsigned int c = h[i * 4] + h[i * 4 + 1] + h[i * 4 + 2] + h[i * 4 + 3];
        if (c) atomicAdd(&hist1[i], c);
    }
}

// ============ two-level deterministic reduce: sums + global min/max ============
__global__ __launch_bounds__(256) void k_reduce_lvl1(
    const double* __restrict__ psum, const double* __restrict__ psumsq,
    const float* __restrict__ tokmin, const float* __restrict__ tokmax,
    double* __restrict__ o1, double* __restrict__ o2,
    float* __restrict__ omn, float* __restrict__ omx)
{
    __shared__ double a[256], b[256];
    __shared__ float c[256], d[256];
    int i = blockIdx.x * 256 + threadIdx.x;
    a[threadIdx.x] = psum[i]; b[threadIdx.x] = psumsq[i];
    c[threadIdx.x] = tokmin[i]; d[threadIdx.x] = tokmax[i];
    __syncthreads();
    for (int st = 128; st > 0; st >>= 1) {
        if (threadIdx.x < st) {
            a[threadIdx.x] += a[threadIdx.x + st];
            b[threadIdx.x] += b[threadIdx.x + st];
            c[threadIdx.x] = fminf(c[threadIdx.x], c[threadIdx.x + st]);
            d[threadIdx.x] = fmaxf(d[threadIdx.x], d[threadIdx.x + st]);
        }
        __syncthreads();
    }
    if (threadIdx.x == 0) { o1[blockIdx.x] = a[0]; o2[blockIdx.x] = b[0];
                            omn[blockIdx.x] = c[0]; omx[blockIdx.x] = d[0]; }
}

__global__ __launch_bounds__(256) void k_reduce_lvl2(
    const double* __restrict__ i1, const double* __restrict__ i2,
    const float* __restrict__ imn, const float* __restrict__ imx,
    double* __restrict__ g_sum, float* __restrict__ fscal)
{
    __shared__ double a[256], b[256];
    __shared__ float c[256], d[256];
    int t = threadIdx.x;
    a[t] = i1[t]; b[t] = i2[t]; c[t] = imn[t]; d[t] = imx[t];
    __syncthreads();
    for (int st = 128; st > 0; st >>= 1) {
        if (t < st) {
            a[t] += a[t + st]; b[t] += b[t + st];
            c[t] = fminf(c[t], c[t + st]); d[t] = fmaxf(d[t], d[t + st]);
        }
        __syncthreads();
    }
    if (t == 0) { g_sum[0] = a[0]; g_sum[1] = b[0]; fscal[3] = c[0]; fscal[4] = d[0]; }
}

// scal layout (u32 at ws+16): [0..1]=unused [2..3]=b1 [4..5]=prefix [6..7]=b2 [8..9]=finkey
__global__ void k_sel1(unsigned int* __restrict__ scal, const unsigned int* __restrict__ hist1)
{
    if (threadIdx.x != 0) return;
    const unsigned long long ranks[2] = {RANK0, RANK1};
    for (int r = 0; r < 2; ++r) {
        unsigned long long k = ranks[r], c = 0; int b = 0;
        for (; b < 2048; ++b) { unsigned int hh = hist1[b]; if (k < c + hh) break; c += hh; }
        scal[2 + r] = (unsigned int)b;
        scal[4 + r] = (unsigned int)c;
    }
}

// ============ radix-select pass B: middle 11 bits ============
__global__ __launch_bounds__(256) void k_hist_mid(const float4* __restrict__ x4,
    const unsigned int* __restrict__ scal, unsigned int* __restrict__ hist2)
{
    __shared__ unsigned int h[2][2048];
    for (int i = threadIdx.x; i < 4096; i += 256) ((unsigned int*)h)[i] = 0;
    __syncthreads();
    const unsigned int t0 = scal[2], t1 = scal[3];
    const long long n4 = NTOT / 4;
    for (long long i = (long long)blockIdx.x * 256 + threadIdx.x; i < n4;
         i += (long long)gridDim.x * 256) {
        float4 v = x4[i];
        #pragma unroll
        for (int c = 0; c < 4; ++c) {
            float f = (c == 0) ? v.x : (c == 1) ? v.y : (c == 2) ? v.z : v.w;
            unsigned int k = f2key(f);
            unsigned int top = k >> 21, mid = (k >> 10) & 2047u;
            if (top == t0) atomicAdd(&h[0][mid], 1u);
            if (top == t1) atomicAdd(&h[1][mid], 1u);
        }
    }
    __syncthreads();
    for (int i = threadIdx.x; i < 2048; i += 256) {
        unsigned int c0 = h[0][i], c1 = h[1][i];
        if (c0) atomicAdd(&hist2[i], c0);
        if (c1) atomicAdd(&hist2[2048 + i], c1);
    }
}

__global__ void k_sel2(unsigned int* __restrict__ scal, const unsigned int* __restrict__ hist2)
{
    if (threadIdx.x != 0) return;
    const unsigned long long ranks[2] = {RANK0, RANK1};
    for (int r = 0; r < 2; ++r) {
        unsigned long long k = ranks[r] - (unsigned long long)scal[4 + r];
        unsigned long long c = 0; int b = 0;
        for (; b < 2048; ++b) { unsigned int hh = hist2[r * 2048 + b]; if (k < c + hh) break; c += hh; }
        scal[6 + r] = (unsigned int)b;
        scal[4 + r] = scal[4 + r] + (unsigned int)c;
    }
}

// ============ radix-select pass C: low 10 bits ============
__global__ __launch_bounds__(256) void k_hist_low(const float4* __restrict__ x4,
    const unsigned int* __restrict__ scal, unsigned int* __restrict__ hist3)
{
    __shared__ unsigned int h[2][1024];
    for (int i = threadIdx.x; i < 2048; i += 256) ((unsigned int*)h)[i] = 0;
    __syncthreads();
    const unsigned int t22_0 = (scal[2] << 11) | scal[6];
    const unsigned int t22_1 = (scal[3] << 11) | scal[7];
    const long long n4 = NTOT / 4;
    for (long long i = (long long)blockIdx.x * 256 + threadIdx.x; i < n4;
         i += (long long)gridDim.x * 256) {
        float4 v = x4[i];
        #pragma unroll
        for (int c = 0; c < 4; ++c) {
            float f = (c == 0) ? v.x : (c == 1) ? v.y : (c == 2) ? v.z : v.w;
            unsigned int k = f2key(f);
            unsigned int top22 = k >> 10, low = k & 1023u;
            if (top22 == t22_0) atomicAdd(&h[0][low], 1u);
            if (top22 == t22_1) atomicAdd(&h[1][low], 1u);
        }
    }
    __syncthreads();
    for (int i = threadIdx.x; i < 1024; i += 256) {
        unsigned int c0 = h[0][i], c1 = h[1][i];
        if (c0) atomicAdd(&hist3[i], c0);
        if (c1) atomicAdd(&hist3[1024 + i], c1);
    }
}

__global__ void k_sel3(unsigned int* __restrict__ scal, float* __restrict__ fscal,
                       const unsigned int* __restrict__ hist3, const double* __restrict__ gsum)
{
    if (threadIdx.x != 0) return;
    const unsigned long long ranks[2] = {RANK0, RANK1};
    for (int r = 0; r < 2; ++r) {
        unsigned long long k = ranks[r] - (unsigned long long)scal[4 + r];
        unsigned long long c = 0; int b = 0;
        for (; b < 1024; ++b) { unsigned int hh = hist3[r * 1024 + b]; if (k < c + hh) break; c += hh; }
        scal[8 + r] = (scal[2 + r] << 21) | (scal[6 + r] << 10) | (unsigned int)b;
    }
    float v0 = key2f(scal[8]), v1 = key2f(scal[9]);
    float mean = __fmul_rn(__fadd_rn(v0, v1), 0.5f);
    double s = gsum[0], ss = gsum[1];
    const double NN = (double)NTOT;
    double var = (ss - s * s / NN) / (NN - 1.0);
    if (var < 0.0) var = 0.0;
    float stdf = (float)sqrt(var);
    float rng = __fsub_rn(fscal[4], fscal[3]);
    float coeff = __fdiv_rn(stdf, rng);
    fscal[0] = mean; fscal[1] = stdf; fscal[2] = coeff;
}

// ============ K2: wave-per-token band counts -> attn_std ============
__global__ __launch_bounds__(256) void k_count(const float4* __restrict__ x4,
    const float* __restrict__ eulg, const float* __restrict__ fscal, float* __restrict__ attn)
{
    const int wave = threadIdx.x >> 6, lane = threadIdx.x & 63;
    const float mean = fscal[0], coeff = fscal[2];
    for (int token = blockIdx.x * 4 + wave; token < NTOK; token += gridDim.x * 4) {
        float band = __fmul_rn(__fmul_rn(eulg[token], coeff), 0.8f);
        float hi = __fadd_rn(mean, band);
        float lo = __fsub_rn(mean, band);
        const float4* xp = x4 + (size_t)token * 192;
        int d = 0;
        #pragma unroll
        for (int k = 0; k < 3; ++k) {
            float4 v = xp[lane + k * 64];
            d += (v.x < hi) - (v.x < lo) + (v.y < hi) - (v.y < lo)
               + (v.z < hi) - (v.z < lo) + (v.w < hi) - (v.w < lo);
        }
        #pragma unroll
        for (int s = 1; s < 64; s <<= 1) d += __shfl_xor(d, s);
        if (lane == 0) {
            float a = fmaxf((float)d, 76.8f);             // clip(.., COCO*C)
            float inv = __fdiv_rn(1.0f, a);
            attn[token] = (inv > 1.0f) ? 0.0f : inv;
        }
    }
}

// ============ K3: per-batch stable sort + score + rank -> levels ============
__device__ inline void bitonic_sort(unsigned long long* keys, int tid) {
    for (int k = 2; k <= TT; k <<= 1) {
        for (int j = k >> 1; j > 0; j >>= 1) {
            __syncthreads();
            for (int i = tid; i < TT; i += 512) {
                int l = i ^ j;
                if (l > i) {
                    unsigned long long a = keys[i], c = keys[l];
                    bool up = ((i & k) == 0);
                    if (up ? (a > c) : (a < c)) { keys[i] = c; keys[l] = a; }
                }
            }
        }
    }
    __syncthreads();
}

__global__ __launch_bounds__(512) void k_sort(const float* __restrict__ eulg,
    const float* __restrict__ attn, const float* __restrict__ fscal,
    unsigned int* __restrict__ nlev)
{
    int b = blockIdx.x, tid = threadIdx.x;
    __shared__ unsigned long long keys[TT];
    __shared__ float av[TT];
    __shared__ int firstNeg;
    __shared__ int s_diff;
    const float stdf = fscal[1];
    const float THR = (float)(1.0 + 511.0 / 254.0);

    for (int t = tid; t < TT; t += 512) {
        float v = eulg[b * TT + t];
        keys[t] = ((unsigned long long)f2key(v) << 32) | (unsigned int)t;  // (value asc, idx asc)
    }
    if (tid == 0) firstNeg = TT;
    __syncthreads();
    bitonic_sort(keys, tid);

    for (int t = tid; t < TT; t += 512)
        av[t] = attn[b * TT + (unsigned int)(keys[t] & 0xffffffffu)];
    __syncthreads();

    for (int i = tid; i < TT; i += 512) {
        float vi = key2f((unsigned int)(keys[i] >> 32));
        float vd = key2f((unsigned int)(keys[TT - 1 - i] >> 32));
        float a  = __fmul_rn(vd, av[TT - 1 - i]);
        float bb = __fmul_rn(__fmul_rn(vi, av[i]), THR);
        float sc = __fdiv_rn(__fsub_rn(a, bb), stdf);
        if (sc < 0.0f) atomicMin(&firstNeg, i);
    }
    __syncthreads();
    if (tid == 0) {
        int mi = (firstNeg >= TT) ? 0 : firstNeg;       // argmax(all False) = 0
        s_diff = (mi - 1 > 0) ? (mi - 1) : 0;
    }
    __syncthreads();
    int diffv = s_diff;

    // second sort: (value desc, idx asc) -> reference-stable descending ranks
    for (int t = tid; t < TT; t += 512) {
        float v = eulg[b * TT + t];
        keys[t] = ((unsigned long long)(unsigned int)(~f2key(v)) << 32) | (unsigned int)t;
    }
    __syncthreads();
    bitonic_sort(keys, tid);

    for (int q = tid; q < TT; q += 512) {
        unsigned int token = (unsigned int)(keys[q] & 0xffffffffu);
        int rank = q;
        unsigned int levels = (rank > TT - 2 - diffv) ? 128u
                            : ((rank <= diffv) ? 512u : 256u);
        nlev[b * TT + token] = levels;
    }
}

// ============ K4: wave-per-token quantize / dequantize ============
__global__ __launch_bounds__(256) void k_quant(const float4* __restrict__ x4,
    const float* __restrict__ tokmin, const float* __restrict__ tokmax,
    const unsigned int* __restrict__ nlev, float4* __restrict__ out)
{
    const int wave = threadIdx.x >> 6, lane = threadIdx.x & 63;
    for (int token = blockIdx.x * 4 + wave; token < NTOK; token += gridDim.x * 4) {
        float mn = tokmin[token], mx = tokmax[token];
        float delta = fmaxf(__fdiv_rn(__fsub_rn(mx, mn), 255.0f), 1e-8f);
        float zp = rintf(__fdiv_rn(-mn, delta));
        float nlm1 = (float)(nlev[token] - 1u);
        const float4* xp = x4 + (size_t)token * 192;
        float4* op = (float4*)out + (size_t)token * 192;
        #pragma unroll
        for (int k = 0; k < 3; ++k) {
            float4 v = xp[lane + k * 64];
            float4 r;
            #pragma unroll
            for (int c = 0; c < 4; ++c) {
                float vv = (c == 0) ? v.x : (c == 1) ? v.y : (c == 2) ? v.z : v.w;
                float xi = __fadd_rn(rintf(__fdiv_rn(vv, delta)), zp);
                float t = __fdiv_rn(xi, nlm1);
                t = fminf(fmaxf(t, 0.0f), 1.0f);
                float xq = __fmul_rn(t, nlm1);
                float o = __fmul_rn(__fsub_rn(xq, zp), delta);
                if (c == 0) r.x = o; else if (c == 1) r.y = o; else if (c == 2) r.z = o; else r.w = o;
            }
            op[lane + k * 64] = r;
        }
    }
}

extern "C" void kernel_launch(void* const* d_in, const int* in_sizes, int n_in,
                              void* d_out, int out_size, void* d_ws, size_t ws_size,
                              hipStream_t stream)
{
    (void)in_sizes; (void)n_in; (void)out_size; (void)ws_size;
    const float* x = (const float*)d_in[0];
    float* out = (float*)d_out;
    char* ws = (char*)d_ws;

    double* g_sum = (double*)ws;                           // [0]=sum [1]=sumsq
    unsigned int* scal = (unsigned int*)(ws + 16);         // 12 u32 slots
    float* fscal = (float*)(ws + 64);                      // mean,std,coeff,gmin,gmax
    unsigned int* hist1 = (unsigned int*)(ws + 128);       // 2048
    unsigned int* hist2 = (unsigned int*)(ws + 8320);      // 2*2048
    unsigned int* hist3 = (unsigned int*)(ws + 24704);     // 2*1024
    float* tokmin = (float*)(ws + 40960);
    float* tokmax = tokmin + NTOK;
    float* eulg   = tokmax + NTOK;
    float* attn   = eulg + NTOK;
    unsigned int* nlev = (unsigned int*)(attn + NTOK);
    double* psum   = (double*)(ws + 1351680);
    double* psumsq = psum + NTOK;                          // ends ws+2400256
    double* p2sum  = psumsq + NTOK;                        // 256 doubles
    double* p2sumsq = p2sum + 256;
    float* p2min = (float*)(p2sumsq + 256);
    float* p2max = p2min + 256;

    hipMemsetAsync(ws, 0, 32896, stream);                  // scalars + histograms

    k_token_stats<<<2048, 256, 0, stream>>>((const float4*)x, tokmin, tokmax,
                                            eulg, psum, psumsq, hist1);
    k_reduce_lvl1<<<256, 256, 0, stream>>>(psum, psumsq, tokmin, tokmax,
                                           p2sum, p2sumsq, p2min, p2max);
    k_reduce_lvl2<<<1, 256, 0, stream>>>(p2sum, p2sumsq, p2min, p2max, g_sum, fscal);
    k_sel1<<<1, 64, 0, stream>>>(scal, hist1);
    k_hist_mid<<<1024, 256, 0, stream>>>((const float4*)x, scal, hist2);
    k_sel2<<<1, 64, 0, stream>>>(scal, hist2);
    k_hist_low<<<1024, 256, 0, stream>>>((const float4*)x, scal, hist3);
    k_sel3<<<1, 64, 0, stream>>>(scal, fscal, hist3, g_sum);
    k_count<<<2048, 256, 0, stream>>>((const float4*)x, eulg, fscal, attn);
    k_sort<<<BB, 512, 0, stream>>>(eulg, attn, fscal, nlev);
    k_quant<<<2048, 256, 0, stream>>>((const float4*)x, tokmin, tokmax, nlev, (float4*)out);
}

// Round 3
// 354.124 us; speedup vs baseline: 6.4352x; 2.1356x over previous
//
#include <hip/hip_runtime.h>
#include <stdint.h>
#include <math.h>

#define BB 32
#define TT 2048
#define CC 768
#define NTOK (BB*TT)                     // 65536
#define NTOT 50331648LL                  // BB*TT*CC
#define RANK0 25165823ULL                // NTOT/2 - 1
#define RANK1 25165824ULL                // NTOT/2

// ---- monotone float<->uint mapping (order-preserving) ----
__device__ inline unsigned int f2key(float f) {
    unsigned int u = __float_as_uint(f);
    return (u & 0x80000000u) ? ~u : (u | 0x80000000u);
}
__device__ inline float key2f(unsigned int k) {
    unsigned int u = (k & 0x80000000u) ? (k ^ 0x80000000u) : ~k;
    return __uint_as_float(u);
}

// ---- parallel bucket select: 256 threads, NB bins, rank k ----
// finds bin b with cumsum(hist[0..b)) <= k < cumsum(hist[0..b]); writes
// bin -> res[0], prefix-count -> res[1] (shared memory of caller).
template<int NB>
__device__ void select_one(const unsigned int* __restrict__ hist,
                           unsigned long long k, unsigned int* res)
{
    const int t = threadIdx.x;                 // 256 threads
    constexpr int PER = NB / 256;
    unsigned int loc[PER];
    unsigned long long lsum = 0;
    #pragma unroll
    for (int i = 0; i < PER; ++i) { loc[i] = hist[t * PER + i]; lsum += loc[i]; }
    __shared__ unsigned long long pscan[256];
    pscan[t] = lsum;
    __syncthreads();
    #pragma unroll
    for (int off = 1; off < 256; off <<= 1) {
        unsigned long long v = (t >= off) ? pscan[t - off] : 0ULL;
        __syncthreads();
        pscan[t] += v;
        __syncthreads();
    }
    unsigned long long excl = (t == 0) ? 0ULL : pscan[t - 1];
    if (k >= excl && k < pscan[t]) {
        unsigned long long c = excl;
        #pragma unroll
        for (int i = 0; i < PER; ++i) {
            if (k < c + loc[i]) { res[0] = (unsigned int)(t * PER + i); res[1] = (unsigned int)c; break; }
            c += loc[i];
        }
    }
    __syncthreads();
}

// ============ K1: wave-per-token stats + fused top-11 histogram ============
__global__ __launch_bounds__(256) void k_token_stats(
    const float4* __restrict__ x4, float* __restrict__ tokmin,
    float* __restrict__ tokmax, float* __restrict__ eulg,
    double* __restrict__ psum, double* __restrict__ psumsq,
    unsigned int* __restrict__ hist1)
{
    __shared__ unsigned int h[2048 * 4];          // 4 sub-hists by (tid&3)
    for (int i = threadIdx.x; i < 8192; i += 256) h[i] = 0;
    __syncthreads();
    const int wave = threadIdx.x >> 6, lane = threadIdx.x & 63;
    const int sub = threadIdx.x & 3;

    for (int token = blockIdx.x * 4 + wave; token < NTOK; token += gridDim.x * 4) {
        const float4* xp = x4 + (size_t)token * 192;
        float mn = INFINITY, mx = -INFINITY;
        double s = 0.0, ss = 0.0;
        #pragma unroll
        for (int k = 0; k < 3; ++k) {
            float4 v = xp[lane + k * 64];
            mn = fminf(mn, fminf(fminf(v.x, v.y), fminf(v.z, v.w)));
            mx = fmaxf(mx, fmaxf(fmaxf(v.x, v.y), fmaxf(v.z, v.w)));
            s  += (double)v.x + (double)v.y + (double)v.z + (double)v.w;
            ss += (double)v.x * (double)v.x + (double)v.y * (double)v.y
                + (double)v.z * (double)v.z + (double)v.w * (double)v.w;
            atomicAdd(&h[((f2key(v.x) >> 21) << 2) + sub], 1u);
            atomicAdd(&h[((f2key(v.y) >> 21) << 2) + sub], 1u);
            atomicAdd(&h[((f2key(v.z) >> 21) << 2) + sub], 1u);
            atomicAdd(&h[((f2key(v.w) >> 21) << 2) + sub], 1u);
        }
        #pragma unroll
        for (int d = 1; d < 64; d <<= 1) {
            mn = fminf(mn, __shfl_xor(mn, d));
            mx = fmaxf(mx, __shfl_xor(mx, d));
            s  += __shfl_xor(s, d);
            ss += __shfl_xor(ss, d);
        }
        if (lane == 0) {
            tokmin[token] = mn; tokmax[token] = mx;
            float e = __fsub_rn(mx, mn);
            if ((token & (TT - 1)) == 0) e = __fmul_rn(e, 1e8f);
            eulg[token] = e;
            psum[token] = s; psumsq[token] = ss;
        }
    }
    __syncthreads();
    for (int i = threadIdx.x; i < 2048; i += 256) {
        unsigned int c = h[i * 4] + h[i * 4 + 1] + h[i * 4 + 2] + h[i * 4 + 3];
        if (c) atomicAdd(&hist1[i], c);
    }
}

// ============ two-level deterministic reduce: sums + global min/max ============
__global__ __launch_bounds__(256) void k_reduce_lvl1(
    const double* __restrict__ psum, const double* __restrict__ psumsq,
    const float* __restrict__ tokmin, const float* __restrict__ tokmax,
    double* __restrict__ o1, double* __restrict__ o2,
    float* __restrict__ omn, float* __restrict__ omx)
{
    __shared__ double a[256], b[256];
    __shared__ float c[256], d[256];
    int i = blockIdx.x * 256 + threadIdx.x;
    a[threadIdx.x] = psum[i]; b[threadIdx.x] = psumsq[i];
    c[threadIdx.x] = tokmin[i]; d[threadIdx.x] = tokmax[i];
    __syncthreads();
    for (int st = 128; st > 0; st >>= 1) {
        if (threadIdx.x < st) {
            a[threadIdx.x] += a[threadIdx.x + st];
            b[threadIdx.x] += b[threadIdx.x + st];
            c[threadIdx.x] = fminf(c[threadIdx.x], c[threadIdx.x + st]);
            d[threadIdx.x] = fmaxf(d[threadIdx.x], d[threadIdx.x + st]);
        }
        __syncthreads();
    }
    if (threadIdx.x == 0) { o1[blockIdx.x] = a[0]; o2[blockIdx.x] = b[0];
                            omn[blockIdx.x] = c[0]; omx[blockIdx.x] = d[0]; }
}

__global__ __launch_bounds__(256) void k_reduce_lvl2(
    const double* __restrict__ i1, const double* __restrict__ i2,
    const float* __restrict__ imn, const float* __restrict__ imx,
    double* __restrict__ g_sum, float* __restrict__ fscal)
{
    __shared__ double a[256], b[256];
    __shared__ float c[256], d[256];
    int t = threadIdx.x;
    a[t] = i1[t]; b[t] = i2[t]; c[t] = imn[t]; d[t] = imx[t];
    __syncthreads();
    for (int st = 128; st > 0; st >>= 1) {
        if (t < st) {
            a[t] += a[t + st]; b[t] += b[t + st];
            c[t] = fminf(c[t], c[t + st]); d[t] = fmaxf(d[t], d[t + st]);
        }
        __syncthreads();
    }
    if (t == 0) { g_sum[0] = a[0]; g_sum[1] = b[0]; fscal[3] = c[0]; fscal[4] = d[0]; }
}

// scal layout (u32 at ws+16): [2..3]=b1 [4..5]=prefix [6..7]=b2 [8..9]=finkey
__global__ __launch_bounds__(256) void k_sel1(unsigned int* __restrict__ scal,
                                              const unsigned int* __restrict__ hist1)
{
    __shared__ unsigned int res[2][2];
    select_one<2048>(hist1, RANK0, res[0]);
    select_one<2048>(hist1, RANK1, res[1]);
    if (threadIdx.x == 0) {
        scal[2] = res[0][0]; scal[4] = res[0][1];
        scal[3] = res[1][0]; scal[5] = res[1][1];
    }
}

// ============ radix-select pass B: middle 11 bits ============
__global__ __launch_bounds__(256) void k_hist_mid(const float4* __restrict__ x4,
    const unsigned int* __restrict__ scal, unsigned int* __restrict__ hist2)
{
    __shared__ unsigned int h[2][2048];
    for (int i = threadIdx.x; i < 4096; i += 256) ((unsigned int*)h)[i] = 0;
    __syncthreads();
    const unsigned int t0 = scal[2], t1 = scal[3];
    const long long n4 = NTOT / 4;
    for (long long i = (long long)blockIdx.x * 256 + threadIdx.x; i < n4;
         i += (long long)gridDim.x * 256) {
        float4 v = x4[i];
        #pragma unroll
        for (int c = 0; c < 4; ++c) {
            float f = (c == 0) ? v.x : (c == 1) ? v.y : (c == 2) ? v.z : v.w;
            unsigned int k = f2key(f);
            unsigned int top = k >> 21, mid = (k >> 10) & 2047u;
            if (top == t0) atomicAdd(&h[0][mid], 1u);
            if (top == t1) atomicAdd(&h[1][mid], 1u);
        }
    }
    __syncthreads();
    for (int i = threadIdx.x; i < 2048; i += 256) {
        unsigned int c0 = h[0][i], c1 = h[1][i];
        if (c0) atomicAdd(&hist2[i], c0);
        if (c1) atomicAdd(&hist2[2048 + i], c1);
    }
}

__global__ __launch_bounds__(256) void k_sel2(unsigned int* __restrict__ scal,
                                              const unsigned int* __restrict__ hist2)
{
    __shared__ unsigned int res[2][2];
    unsigned int p0 = scal[4], p1 = scal[5];
    select_one<2048>(hist2,        RANK0 - p0, res[0]);
    select_one<2048>(hist2 + 2048, RANK1 - p1, res[1]);
    if (threadIdx.x == 0) {
        scal[6] = res[0][0]; scal[4] = p0 + res[0][1];
        scal[7] = res[1][0]; scal[5] = p1 + res[1][1];
    }
}

// ============ radix-select pass C: low 10 bits ============
__global__ __launch_bounds__(256) void k_hist_low(const float4* __restrict__ x4,
    const unsigned int* __restrict__ scal, unsigned int* __restrict__ hist3)
{
    __shared__ unsigned int h[2][1024];
    for (int i = threadIdx.x; i < 2048; i += 256) ((unsigned int*)h)[i] = 0;
    __syncthreads();
    const unsigned int t22_0 = (scal[2] << 11) | scal[6];
    const unsigned int t22_1 = (scal[3] << 11) | scal[7];
    const long long n4 = NTOT / 4;
    for (long long i = (long long)blockIdx.x * 256 + threadIdx.x; i < n4;
         i += (long long)gridDim.x * 256) {
        float4 v = x4[i];
        #pragma unroll
        for (int c = 0; c < 4; ++c) {
            float f = (c == 0) ? v.x : (c == 1) ? v.y : (c == 2) ? v.z : v.w;
            unsigned int k = f2key(f);
            unsigned int top22 = k >> 10, low = k & 1023u;
            if (top22 == t22_0) atomicAdd(&h[0][low], 1u);
            if (top22 == t22_1) atomicAdd(&h[1][low], 1u);
        }
    }
    __syncthreads();
    for (int i = threadIdx.x; i < 1024; i += 256) {
        unsigned int c0 = h[0][i], c1 = h[1][i];
        if (c0) atomicAdd(&hist3[i], c0);
        if (c1) atomicAdd(&hist3[1024 + i], c1);
    }
}

__global__ __launch_bounds__(256) void k_sel3(unsigned int* __restrict__ scal,
    float* __restrict__ fscal, const unsigned int* __restrict__ hist3,
    const double* __restrict__ gsum)
{
    __shared__ unsigned int res[2][2];
    unsigned int p0 = scal[4], p1 = scal[5];
    select_one<1024>(hist3,        RANK0 - p0, res[0]);
    select_one<1024>(hist3 + 1024, RANK1 - p1, res[1]);
    if (threadIdx.x == 0) {
        unsigned int key0 = (scal[2] << 21) | (scal[6] << 10) | res[0][0];
        unsigned int key1 = (scal[3] << 21) | (scal[7] << 10) | res[1][0];
        float v0 = key2f(key0), v1 = key2f(key1);
        float mean = __fmul_rn(__fadd_rn(v0, v1), 0.5f);
        double s = gsum[0], ss = gsum[1];
        const double NN = (double)NTOT;
        double var = (ss - s * s / NN) / (NN - 1.0);
        if (var < 0.0) var = 0.0;
        float stdf = (float)sqrt(var);
        float rng = __fsub_rn(fscal[4], fscal[3]);
        float coeff = __fdiv_rn(stdf, rng);
        fscal[0] = mean; fscal[1] = stdf; fscal[2] = coeff;
    }
}

// ============ K2: wave-per-token band counts -> attn_std ============
__global__ __launch_bounds__(256) void k_count(const float4* __restrict__ x4,
    const float* __restrict__ eulg, const float* __restrict__ fscal, float* __restrict__ attn)
{
    const int wave = threadIdx.x >> 6, lane = threadIdx.x & 63;
    const float mean = fscal[0], coeff = fscal[2];
    for (int token = blockIdx.x * 4 + wave; token < NTOK; token += gridDim.x * 4) {
        float band = __fmul_rn(__fmul_rn(eulg[token], coeff), 0.8f);
        float hi = __fadd_rn(mean, band);
        float lo = __fsub_rn(mean, band);
        const float4* xp = x4 + (size_t)token * 192;
        int d = 0;
        #pragma unroll
        for (int k = 0; k < 3; ++k) {
            float4 v = xp[lane + k * 64];
            d += (v.x < hi) - (v.x < lo) + (v.y < hi) - (v.y < lo)
               + (v.z < hi) - (v.z < lo) + (v.w < hi) - (v.w < lo);
        }
        #pragma unroll
        for (int s = 1; s < 64; s <<= 1) d += __shfl_xor(d, s);
        if (lane == 0) {
            float a = fmaxf((float)d, 76.8f);             // clip(.., COCO*C)
            float inv = __fdiv_rn(1.0f, a);
            attn[token] = (inv > 1.0f) ? 0.0f : inv;
        }
    }
}

// ============ K3: per-batch stable sort + score + rank -> levels ============
__device__ inline void bitonic_sort(unsigned long long* keys, int tid) {
    for (int k = 2; k <= TT; k <<= 1) {
        for (int j = k >> 1; j > 0; j >>= 1) {
            __syncthreads();
            for (int i = tid; i < TT; i += 512) {
                int l = i ^ j;
                if (l > i) {
                    unsigned long long a = keys[i], c = keys[l];
                    bool up = ((i & k) == 0);
                    if (up ? (a > c) : (a < c)) { keys[i] = c; keys[l] = a; }
                }
            }
        }
    }
    __syncthreads();
}

__global__ __launch_bounds__(512) void k_sort(const float* __restrict__ eulg,
    const float* __restrict__ attn, const float* __restrict__ fscal,
    unsigned int* __restrict__ nlev)
{
    int b = blockIdx.x, tid = threadIdx.x;
    __shared__ unsigned long long keys[TT];
    __shared__ float av[TT];
    __shared__ int firstNeg;
    __shared__ int s_diff;
    const float stdf = fscal[1];
    const float THR = (float)(1.0 + 511.0 / 254.0);

    for (int t = tid; t < TT; t += 512) {
        float v = eulg[b * TT + t];
        keys[t] = ((unsigned long long)f2key(v) << 32) | (unsigned int)t;  // (value asc, idx asc)
    }
    if (tid == 0) firstNeg = TT;
    __syncthreads();
    bitonic_sort(keys, tid);

    for (int t = tid; t < TT; t += 512)
        av[t] = attn[b * TT + (unsigned int)(keys[t] & 0xffffffffu)];
    __syncthreads();

    for (int i = tid; i < TT; i += 512) {
        float vi = key2f((unsigned int)(keys[i] >> 32));
        float vd = key2f((unsigned int)(keys[TT - 1 - i] >> 32));
        float a  = __fmul_rn(vd, av[TT - 1 - i]);
        float bb = __fmul_rn(__fmul_rn(vi, av[i]), THR);
        float sc = __fdiv_rn(__fsub_rn(a, bb), stdf);
        if (sc < 0.0f) atomicMin(&firstNeg, i);
    }
    __syncthreads();
    if (tid == 0) {
        int mi = (firstNeg >= TT) ? 0 : firstNeg;       // argmax(all False) = 0
        s_diff = (mi - 1 > 0) ? (mi - 1) : 0;
    }
    __syncthreads();
    int diffv = s_diff;

    // second sort: (value desc, idx asc) -> reference-stable descending ranks
    for (int t = tid; t < TT; t += 512) {
        float v = eulg[b * TT + t];
        keys[t] = ((unsigned long long)(unsigned int)(~f2key(v)) << 32) | (unsigned int)t;
    }
    __syncthreads();
    bitonic_sort(keys, tid);

    for (int q = tid; q < TT; q += 512) {
        unsigned int token = (unsigned int)(keys[q] & 0xffffffffu);
        int rank = q;
        unsigned int levels = (rank > TT - 2 - diffv) ? 128u
                            : ((rank <= diffv) ? 512u : 256u);
        nlev[b * TT + token] = levels;
    }
}

// ============ K4: wave-per-token quantize / dequantize ============
__global__ __launch_bounds__(256) void k_quant(const float4* __restrict__ x4,
    const float* __restrict__ tokmin, const float* __restrict__ tokmax,
    const unsigned int* __restrict__ nlev, float4* __restrict__ out)
{
    const int wave = threadIdx.x >> 6, lane = threadIdx.x & 63;
    for (int token = blockIdx.x * 4 + wave; token < NTOK; token += gridDim.x * 4) {
        float mn = tokmin[token], mx = tokmax[token];
        float delta = fmaxf(__fdiv_rn(__fsub_rn(mx, mn), 255.0f), 1e-8f);
        float zp = rintf(__fdiv_rn(-mn, delta));
        float nlm1 = (float)(nlev[token] - 1u);
        const float4* xp = x4 + (size_t)token * 192;
        float4* op = (float4*)out + (size_t)token * 192;
        #pragma unroll
        for (int k = 0; k < 3; ++k) {
            float4 v = xp[lane + k * 64];
            float4 r;
            #pragma unroll
            for (int c = 0; c < 4; ++c) {
                float vv = (c == 0) ? v.x : (c == 1) ? v.y : (c == 2) ? v.z : v.w;
                float xi = __fadd_rn(rintf(__fdiv_rn(vv, delta)), zp);
                float t = __fdiv_rn(xi, nlm1);
                t = fminf(fmaxf(t, 0.0f), 1.0f);
                float xq = __fmul_rn(t, nlm1);
                float o = __fmul_rn(__fsub_rn(xq, zp), delta);
                if (c == 0) r.x = o; else if (c == 1) r.y = o; else if (c == 2) r.z = o; else r.w = o;
            }
            op[lane + k * 64] = r;
        }
    }
}

extern "C" void kernel_launch(void* const* d_in, const int* in_sizes, int n_in,
                              void* d_out, int out_size, void* d_ws, size_t ws_size,
                              hipStream_t stream)
{
    (void)in_sizes; (void)n_in; (void)out_size; (void)ws_size;
    const float* x = (const float*)d_in[0];
    float* out = (float*)d_out;
    char* ws = (char*)d_ws;

    double* g_sum = (double*)ws;                           // [0]=sum [1]=sumsq
    unsigned int* scal = (unsigned int*)(ws + 16);         // 12 u32 slots
    float* fscal = (float*)(ws + 64);                      // mean,std,coeff,gmin,gmax
    unsigned int* hist1 = (unsigned int*)(ws + 128);       // 2048
    unsigned int* hist2 = (unsigned int*)(ws + 8320);      // 2*2048
    unsigned int* hist3 = (unsigned int*)(ws + 24704);     // 2*1024
    float* tokmin = (float*)(ws + 40960);
    float* tokmax = tokmin + NTOK;
    float* eulg   = tokmax + NTOK;
    float* attn   = eulg + NTOK;
    unsigned int* nlev = (unsigned int*)(attn + NTOK);
    double* psum   = (double*)(ws + 1351680);
    double* psumsq = psum + NTOK;                          // ends ws+2400256
    double* p2sum  = psumsq + NTOK;                        // 256 doubles
    double* p2sumsq = p2sum + 256;
    float* p2min = (float*)(p2sumsq + 256);
    float* p2max = p2min + 256;

    hipMemsetAsync(ws, 0, 32896, stream);                  // scalars + histograms

    k_token_stats<<<2048, 256, 0, stream>>>((const float4*)x, tokmin, tokmax,
                                            eulg, psum, psumsq, hist1);
    k_reduce_lvl1<<<256, 256, 0, stream>>>(psum, psumsq, tokmin, tokmax,
                                           p2sum, p2sumsq, p2min, p2max);
    k_reduce_lvl2<<<1, 256, 0, stream>>>(p2sum, p2sumsq, p2min, p2max, g_sum, fscal);
    k_sel1<<<1, 256, 0, stream>>>(scal, hist1);
    k_hist_mid<<<1024, 256, 0, stream>>>((const float4*)x, scal, hist2);
    k_sel2<<<1, 256, 0, stream>>>(scal, hist2);
    k_hist_low<<<1024, 256, 0, stream>>>((const float4*)x, scal, hist3);
    k_sel3<<<1, 256, 0, stream>>>(scal, fscal, hist3, g_sum);
    k_count<<<2048, 256, 0, stream>>>((const float4*)x, eulg, fscal, attn);
    k_sort<<<BB, 512, 0, stream>>>(eulg, attn, fscal, nlev);
    k_quant<<<2048, 256, 0, stream>>>((const float4*)x, tokmin, tokmax, nlev, (float4*)out);
}

// Round 4
// 293.016 us; speedup vs baseline: 7.7773x; 1.2085x over previous
//
#include <hip/hip_runtime.h>
#include <stdint.h>
#include <math.h>

#define BB 32
#define TT 2048
#define CC 768
#define NTOK (BB*TT)                     // 65536
#define NTOT 50331648LL                  // BB*TT*CC
#define RANK0 25165823ULL                // NTOT/2 - 1
#define RANK1 25165824ULL                // NTOT/2
#define COMPACT_TH 0.0009765625f         // 2^-10: |v| < th  <=>  float exponent <= 116
#define LBUF_CAP 512

// ---- monotone float<->uint mapping (order-preserving) ----
__device__ inline unsigned int f2key(float f) {
    unsigned int u = __float_as_uint(f);
    return (u & 0x80000000u) ? ~u : (u | 0x80000000u);
}
__device__ inline float key2f(unsigned int k) {
    unsigned int u = (k & 0x80000000u) ? (k ^ 0x80000000u) : ~k;
    return __uint_as_float(u);
}

// ---- parallel bucket select: 256 threads, NB bins, rank k ----
template<int NB>
__device__ void select_one(const unsigned int* __restrict__ hist,
                           unsigned long long k, unsigned int* res)
{
    const int t = threadIdx.x;                 // 256 threads
    constexpr int PER = NB / 256;
    unsigned int loc[PER];
    unsigned long long lsum = 0;
    #pragma unroll
    for (int i = 0; i < PER; ++i) { loc[i] = hist[t * PER + i]; lsum += loc[i]; }
    __shared__ unsigned long long pscan[256];
    pscan[t] = lsum;
    __syncthreads();
    #pragma unroll
    for (int off = 1; off < 256; off <<= 1) {
        unsigned long long v = (t >= off) ? pscan[t - off] : 0ULL;
        __syncthreads();
        pscan[t] += v;
        __syncthreads();
    }
    unsigned long long excl = (t == 0) ? 0ULL : pscan[t - 1];
    if (k >= excl && k < pscan[t]) {
        unsigned long long c = excl;
        #pragma unroll
        for (int i = 0; i < PER; ++i) {
            if (k < c + loc[i]) { res[0] = (unsigned int)(t * PER + i); res[1] = (unsigned int)c; break; }
            c += loc[i];
        }
    }
    __syncthreads();
}

// ============ K1: wave-per-token stats + top-11 hist + speculative compact ============
__global__ __launch_bounds__(256) void k_token_stats(
    const float4* __restrict__ x4, float* __restrict__ tokmin,
    float* __restrict__ tokmax, float* __restrict__ eulg,
    double* __restrict__ pS, double* __restrict__ pSS,
    float* __restrict__ pMn, float* __restrict__ pMx,
    unsigned int* __restrict__ hist1, unsigned int* __restrict__ cbuf,
    unsigned int* __restrict__ cnt, unsigned int* __restrict__ scal,
    unsigned int cap)
{
    __shared__ unsigned int h[2048 * 4];          // 4 sub-hists by (tid&3)
    __shared__ unsigned int lbuf[LBUF_CAP];
    __shared__ unsigned int lcnt, lbase;
    __shared__ double wS[4], wSS[4];
    __shared__ float wMn[4], wMx[4];
    for (int i = threadIdx.x; i < 8192; i += 256) h[i] = 0;
    if (threadIdx.x == 0) lcnt = 0;
    __syncthreads();
    const int wave = threadIdx.x >> 6, lane = threadIdx.x & 63;
    const int sub = threadIdx.x & 3;

    double accS = 0.0, accSS = 0.0;
    float gmn = INFINITY, gmx = -INFINITY;

    for (int token = blockIdx.x * 4 + wave; token < NTOK; token += gridDim.x * 4) {
        const float4* xp = x4 + (size_t)token * 192;
        float mn = INFINITY, mx = -INFINITY;
        #pragma unroll
        for (int k = 0; k < 3; ++k) {
            float4 v = xp[lane + k * 64];
            #pragma unroll
            for (int c = 0; c < 4; ++c) {
                float vv = (c == 0) ? v.x : (c == 1) ? v.y : (c == 2) ? v.z : v.w;
                mn = fminf(mn, vv); mx = fmaxf(mx, vv);
                accS += (double)vv;
                accSS += (double)vv * (double)vv;
                unsigned int key = f2key(vv);
                atomicAdd(&h[((key >> 21) << 2) + sub], 1u);
                if (fabsf(vv) < COMPACT_TH) {
                    unsigned int p = atomicAdd(&lcnt, 1u);
                    if (p < LBUF_CAP) lbuf[p] = key;
                }
            }
        }
        gmn = fminf(gmn, mn); gmx = fmaxf(gmx, mx);
        #pragma unroll
        for (int d = 1; d < 64; d <<= 1) {
            mn = fminf(mn, __shfl_xor(mn, d));
            mx = fmaxf(mx, __shfl_xor(mx, d));
        }
        if (lane == 0) {
            tokmin[token] = mn; tokmax[token] = mx;
            float e = __fsub_rn(mx, mn);
            if ((token & (TT - 1)) == 0) e = __fmul_rn(e, 1e8f);
            eulg[token] = e;
        }
    }
    // wave-level reduce of running accumulators
    #pragma unroll
    for (int d = 1; d < 64; d <<= 1) {
        accS  += __shfl_xor(accS, d);
        accSS += __shfl_xor(accSS, d);
        gmn = fminf(gmn, __shfl_xor(gmn, d));
        gmx = fmaxf(gmx, __shfl_xor(gmx, d));
    }
    if (lane == 0) { wS[wave] = accS; wSS[wave] = accSS; wMn[wave] = gmn; wMx[wave] = gmx; }
    __syncthreads();
    if (threadIdx.x == 0) {
        pS[blockIdx.x]  = wS[0] + wS[1] + wS[2] + wS[3];
        pSS[blockIdx.x] = wSS[0] + wSS[1] + wSS[2] + wSS[3];
        pMn[blockIdx.x] = fminf(fminf(wMn[0], wMn[1]), fminf(wMn[2], wMn[3]));
        pMx[blockIdx.x] = fmaxf(fmaxf(wMx[0], wMx[1]), fmaxf(wMx[2], wMx[3]));
        unsigned int n = lcnt;
        if (n > LBUF_CAP) { scal[10] = 1; n = LBUF_CAP; }
        unsigned int base = atomicAdd(&cnt[0], n);
        if (base + n > cap) scal[10] = 1;
        lbase = base; lcnt = n;
    }
    __syncthreads();
    {
        unsigned int n = lcnt, base = lbase;
        for (unsigned int i = threadIdx.x; i < n; i += 256) {
            unsigned int p = base + i;
            if (p < cap) cbuf[p] = lbuf[i];
        }
    }
    for (int i = threadIdx.x; i < 2048; i += 256) {
        unsigned int c = h[i * 4] + h[i * 4 + 1] + h[i * 4 + 2] + h[i * 4 + 3];
        if (c) atomicAdd(&hist1[i], c);
    }
}

// ============ single-block final reduce over 2048 block partials ============
__global__ __launch_bounds__(1024) void k_reduce_final(
    const double* __restrict__ pS, const double* __restrict__ pSS,
    const float* __restrict__ pMn, const float* __restrict__ pMx,
    double* __restrict__ g_sum, float* __restrict__ fscal)
{
    __shared__ double a[1024], b[1024];
    __shared__ float c[1024], d[1024];
    int t = threadIdx.x;
    a[t] = pS[t] + pS[t + 1024];
    b[t] = pSS[t] + pSS[t + 1024];
    c[t] = fminf(pMn[t], pMn[t + 1024]);
    d[t] = fmaxf(pMx[t], pMx[t + 1024]);
    __syncthreads();
    for (int st = 512; st > 0; st >>= 1) {
        if (t < st) {
            a[t] += a[t + st]; b[t] += b[t + st];
            c[t] = fminf(c[t], c[t + st]); d[t] = fmaxf(d[t], d[t + st]);
        }
        __syncthreads();
    }
    if (t == 0) { g_sum[0] = a[0]; g_sum[1] = b[0]; fscal[3] = c[0]; fscal[4] = d[0]; }
}

// scal layout (u32 at ws+16): [2..3]=bucket [4..5]=prefix [8..9]=final key [10]=fallback flag
__global__ __launch_bounds__(256) void k_sel1(unsigned int* __restrict__ scal,
                                              const unsigned int* __restrict__ hist1)
{
    __shared__ unsigned int res[2][2];
    select_one<2048>(hist1, RANK0, res[0]);
    select_one<2048>(hist1, RANK1, res[1]);
    if (threadIdx.x == 0) {
        scal[2] = res[0][0]; scal[4] = res[0][1];
        scal[3] = res[1][0]; scal[5] = res[1][1];
        // bucket fully inside |v| < 2^-10  <=>  float exponent field <= 116
        #pragma unroll
        for (int r = 0; r < 2; ++r) {
            unsigned int bkt = scal[2 + r];
            int e = (bkt >= 1024) ? (int)((bkt >> 2) & 0xFF) : (int)(255 - ((bkt >> 2) & 0xFF));
            if (e > 116) scal[10] = 1;
        }
    }
}

// ============ exact median keys from compacted candidates (flag==0 path) ============
__global__ __launch_bounds__(256) void k_final_sel(unsigned int* __restrict__ scal,
    const unsigned int* __restrict__ cnt, const unsigned int* __restrict__ cbuf,
    unsigned int cap)
{
    if (scal[10]) return;                       // uniform across block
    const int r = blockIdx.x;
    const unsigned int b = scal[2 + r];
    unsigned long long rin = (r ? RANK1 : RANK0) - (unsigned long long)scal[4 + r];
    const unsigned int n = min(cnt[0], cap);
    __shared__ unsigned int h2[2048];
    __shared__ unsigned int res[2];
    for (int i = threadIdx.x; i < 2048; i += 256) h2[i] = 0;
    __syncthreads();
    for (unsigned int i = threadIdx.x; i < n; i += 256) {
        unsigned int k = cbuf[i];
        if ((k >> 21) == b) atomicAdd(&h2[(k >> 10) & 2047u], 1u);
    }
    __syncthreads();
    select_one<2048>(h2, rin, res);
    unsigned int b2 = res[0];
    rin -= res[1];
    for (int i = threadIdx.x; i < 1024; i += 256) h2[i] = 0;
    __syncthreads();
    const unsigned int top22 = (b << 11) | b2;
    for (unsigned int i = threadIdx.x; i < n; i += 256) {
        unsigned int k = cbuf[i];
        if ((k >> 10) == top22) atomicAdd(&h2[k & 1023u], 1u);
    }
    __syncthreads();
    select_one<1024>(h2, rin, res);
    if (threadIdx.x == 0) scal[8 + r] = (b << 21) | (b2 << 10) | res[0];
}

// ============ correctness fallback (early-exits when flag==0; never hit for bench input) ============
__global__ __launch_bounds__(256) void k_fallback(const float4* __restrict__ x4,
                                                  unsigned int* __restrict__ scal)
{
    if (!scal[10]) return;                      // uniform
    const int r = blockIdx.x;
    const unsigned int b = scal[2 + r];
    unsigned long long rin = (r ? RANK1 : RANK0) - (unsigned long long)scal[4 + r];
    __shared__ unsigned int h2[2048];
    __shared__ unsigned int res[2];
    for (int i = threadIdx.x; i < 2048; i += 256) h2[i] = 0;
    __syncthreads();
    const long long n4 = NTOT / 4;
    for (long long i = threadIdx.x; i < n4; i += 256) {
        float4 v = x4[i];
        #pragma unroll
        for (int c = 0; c < 4; ++c) {
            float f = (c == 0) ? v.x : (c == 1) ? v.y : (c == 2) ? v.z : v.w;
            unsigned int k = f2key(f);
            if ((k >> 21) == b) atomicAdd(&h2[(k >> 10) & 2047u], 1u);
        }
    }
    __syncthreads();
    select_one<2048>(h2, rin, res);
    unsigned int b2 = res[0];
    rin -= res[1];
    for (int i = threadIdx.x; i < 1024; i += 256) h2[i] = 0;
    __syncthreads();
    const unsigned int top22 = (b << 11) | b2;
    for (long long i = threadIdx.x; i < n4; i += 256) {
        float4 v = x4[i];
        #pragma unroll
        for (int c = 0; c < 4; ++c) {
            float f = (c == 0) ? v.x : (c == 1) ? v.y : (c == 2) ? v.z : v.w;
            unsigned int k = f2key(f);
            if ((k >> 10) == top22) atomicAdd(&h2[k & 1023u], 1u);
        }
    }
    __syncthreads();
    select_one<1024>(h2, rin, res);
    if (threadIdx.x == 0) scal[8 + r] = (b << 21) | (b2 << 10) | res[0];
}

// ============ scalar stats: mean/std/coeff ============
__global__ void k_finstats(const unsigned int* __restrict__ scal,
                           const double* __restrict__ g_sum, float* __restrict__ fscal)
{
    if (threadIdx.x != 0) return;
    float v0 = key2f(scal[8]), v1 = key2f(scal[9]);
    float mean = __fmul_rn(__fadd_rn(v0, v1), 0.5f);
    double s = g_sum[0], ss = g_sum[1];
    const double NN = (double)NTOT;
    double var = (ss - s * s / NN) / (NN - 1.0);
    if (var < 0.0) var = 0.0;
    float stdf = (float)sqrt(var);
    float rng = __fsub_rn(fscal[4], fscal[3]);
    float coeff = __fdiv_rn(stdf, rng);
    fscal[0] = mean; fscal[1] = stdf; fscal[2] = coeff;
}

// ============ K2: wave-per-token band counts -> attn_std ============
__global__ __launch_bounds__(256) void k_count(const float4* __restrict__ x4,
    const float* __restrict__ eulg, const float* __restrict__ fscal, float* __restrict__ attn)
{
    const int wave = threadIdx.x >> 6, lane = threadIdx.x & 63;
    const float mean = fscal[0], coeff = fscal[2];
    for (int token = blockIdx.x * 4 + wave; token < NTOK; token += gridDim.x * 4) {
        float band = __fmul_rn(__fmul_rn(eulg[token], coeff), 0.8f);
        float hi = __fadd_rn(mean, band);
        float lo = __fsub_rn(mean, band);
        const float4* xp = x4 + (size_t)token * 192;
        int d = 0;
        #pragma unroll
        for (int k = 0; k < 3; ++k) {
            float4 v = xp[lane + k * 64];
            d += (v.x < hi) - (v.x < lo) + (v.y < hi) - (v.y < lo)
               + (v.z < hi) - (v.z < lo) + (v.w < hi) - (v.w < lo);
        }
        #pragma unroll
        for (int s = 1; s < 64; s <<= 1) d += __shfl_xor(d, s);
        if (lane == 0) {
            float a = fmaxf((float)d, 76.8f);             // clip(.., COCO*C)
            float inv = __fdiv_rn(1.0f, a);
            attn[token] = (inv > 1.0f) ? 0.0f : inv;
        }
    }
}

// ============ K3: per-batch stable sort + score + binary-search desc ranks ============
__device__ inline void bitonic_sort(unsigned long long* keys, int tid, int nthr) {
    for (int k = 2; k <= TT; k <<= 1) {
        for (int j = k >> 1; j > 0; j >>= 1) {
            __syncthreads();
            for (int i = tid; i < TT; i += nthr) {
                int l = i ^ j;
                if (l > i) {
                    unsigned long long a = keys[i], c = keys[l];
                    bool up = ((i & k) == 0);
                    if (up ? (a > c) : (a < c)) { keys[i] = c; keys[l] = a; }
                }
            }
        }
    }
    __syncthreads();
}

__global__ __launch_bounds__(1024) void k_sort(const float* __restrict__ eulg,
    const float* __restrict__ attn, const float* __restrict__ fscal,
    unsigned int* __restrict__ nlev)
{
    int bb = blockIdx.x, tid = threadIdx.x;
    __shared__ unsigned long long keys[TT];
    __shared__ float av[TT];
    __shared__ int firstNeg;
    __shared__ int s_diff;
    const float stdf = fscal[1];
    const float THR = (float)(1.0 + 511.0 / 254.0);

    for (int t = tid; t < TT; t += 1024) {
        float v = eulg[bb * TT + t];
        keys[t] = ((unsigned long long)f2key(v) << 32) | (unsigned int)t;  // (value asc, idx asc)
    }
    if (tid == 0) firstNeg = TT;
    __syncthreads();
    bitonic_sort(keys, tid, 1024);

    for (int t = tid; t < TT; t += 1024)
        av[t] = attn[bb * TT + (unsigned int)(keys[t] & 0xffffffffu)];
    __syncthreads();

    for (int i = tid; i < TT; i += 1024) {
        float vi = key2f((unsigned int)(keys[i] >> 32));
        float vd = key2f((unsigned int)(keys[TT - 1 - i] >> 32));
        float a  = __fmul_rn(vd, av[TT - 1 - i]);
        float bt = __fmul_rn(__fmul_rn(vi, av[i]), THR);
        float sc = __fdiv_rn(__fsub_rn(a, bt), stdf);
        if (sc < 0.0f) atomicMin(&firstNeg, i);
    }
    __syncthreads();
    if (tid == 0) {
        int mi = (firstNeg >= TT) ? 0 : firstNeg;       // argmax(all False) = 0
        s_diff = (mi - 1 > 0) ? (mi - 1) : 0;
    }
    __syncthreads();
    int diffv = s_diff;

    // descending-stable rank via tie-group binary search:
    // group [a, b1) ascending; desc position = TT - b1 + (p - a)
    for (int i = tid; i < TT; i += 1024) {
        unsigned long long key = keys[i];
        unsigned int ku = (unsigned int)(key >> 32);
        unsigned long long tlo = ((unsigned long long)ku) << 32;
        int a = 0;
        for (int st = 1024; st > 0; st >>= 1) {
            int c = a + st;
            if (c <= TT && keys[c - 1] < tlo) a = c;
        }
        int b1;
        if (ku == 0xFFFFFFFFu) b1 = TT;
        else {
            unsigned long long thi = ((unsigned long long)(ku + 1)) << 32;
            b1 = 0;
            for (int st = 1024; st > 0; st >>= 1) {
                int c = b1 + st;
                if (c <= TT && keys[c - 1] < thi) b1 = c;
            }
        }
        int rank = TT - b1 + i - a;
        unsigned int token = (unsigned int)(key & 0xffffffffu);
        unsigned int levels = (rank > TT - 2 - diffv) ? 128u
                            : ((rank <= diffv) ? 512u : 256u);
        nlev[bb * TT + token] = levels;
    }
}

// ============ K4: wave-per-token quantize / dequantize ============
__global__ __launch_bounds__(256) void k_quant(const float4* __restrict__ x4,
    const float* __restrict__ tokmin, const float* __restrict__ tokmax,
    const unsigned int* __restrict__ nlev, float4* __restrict__ out)
{
    const int wave = threadIdx.x >> 6, lane = threadIdx.x & 63;
    for (int token = blockIdx.x * 4 + wave; token < NTOK; token += gridDim.x * 4) {
        float mn = tokmin[token], mx = tokmax[token];
        float delta = fmaxf(__fdiv_rn(__fsub_rn(mx, mn), 255.0f), 1e-8f);
        float zp = rintf(__fdiv_rn(-mn, delta));
        float nlm1 = (float)(nlev[token] - 1u);
        const float4* xp = x4 + (size_t)token * 192;
        float4* op = (float4*)out + (size_t)token * 192;
        #pragma unroll
        for (int k = 0; k < 3; ++k) {
            float4 v = xp[lane + k * 64];
            float4 r;
            #pragma unroll
            for (int c = 0; c < 4; ++c) {
                float vv = (c == 0) ? v.x : (c == 1) ? v.y : (c == 2) ? v.z : v.w;
                float xi = __fadd_rn(rintf(__fdiv_rn(vv, delta)), zp);
                float t = __fdiv_rn(xi, nlm1);
                t = fminf(fmaxf(t, 0.0f), 1.0f);
                float xq = __fmul_rn(t, nlm1);
                float o = __fmul_rn(__fsub_rn(xq, zp), delta);
                if (c == 0) r.x = o; else if (c == 1) r.y = o; else if (c == 2) r.z = o; else r.w = o;
            }
            op[lane + k * 64] = r;
        }
    }
}

extern "C" void kernel_launch(void* const* d_in, const int* in_sizes, int n_in,
                              void* d_out, int out_size, void* d_ws, size_t ws_size,
                              hipStream_t stream)
{
    (void)in_sizes; (void)n_in; (void)out_size;
    const float* x = (const float*)d_in[0];
    float* out = (float*)d_out;
    char* ws = (char*)d_ws;

    double* g_sum = (double*)ws;                           // [0]=sum [1]=sumsq
    unsigned int* scal = (unsigned int*)(ws + 16);         // 12 u32 slots
    unsigned int* cnt = (unsigned int*)(ws + 64);          // compact counter
    float* fscal = (float*)(ws + 96);                      // mean,std,coeff,gmin,gmax
    unsigned int* hist1 = (unsigned int*)(ws + 128);       // 2048, ends 8320
    float* tokmin = (float*)(ws + 16384);
    float* tokmax = tokmin + NTOK;
    float* eulg   = tokmax + NTOK;
    float* attn   = eulg + NTOK;
    unsigned int* nlev = (unsigned int*)(attn + NTOK);     // ends 1327104
    double* pS  = (double*)(ws + 1327104);                 // 2048 doubles
    double* pSS = pS + 2048;
    float* pMn  = (float*)(pSS + 2048);                    // 2048 floats
    float* pMx  = pMn + 2048;                              // ends 1376256
    unsigned int* cbuf = (unsigned int*)(ws + 1376256);
    unsigned int cap = 0;
    if (ws_size > 1376256 + 4096)
        cap = (unsigned int)min((size_t)(1u << 20), (ws_size - 1376256) / 4);

    hipMemsetAsync(ws, 0, 8320, stream);                   // scalars + cnt + flag + hist1

    k_token_stats<<<2048, 256, 0, stream>>>((const float4*)x, tokmin, tokmax, eulg,
                                            pS, pSS, pMn, pMx, hist1, cbuf, cnt, scal, cap);
    k_reduce_final<<<1, 1024, 0, stream>>>(pS, pSS, pMn, pMx, g_sum, fscal);
    k_sel1<<<1, 256, 0, stream>>>(scal, hist1);
    k_final_sel<<<2, 256, 0, stream>>>(scal, cnt, cbuf, cap);
    k_fallback<<<2, 256, 0, stream>>>((const float4*)x, scal);
    k_finstats<<<1, 64, 0, stream>>>(scal, g_sum, fscal);
    k_count<<<2048, 256, 0, stream>>>((const float4*)x, eulg, fscal, attn);
    k_sort<<<BB, 1024, 0, stream>>>(eulg, attn, fscal, nlev);
    k_quant<<<2048, 256, 0, stream>>>((const float4*)x, tokmin, tokmax, nlev, (float4*)out);
}

// Round 6
// 266.476 us; speedup vs baseline: 8.5519x; 1.0996x over previous
//
#include <hip/hip_runtime.h>
#include <stdint.h>
#include <math.h>

#define BB 32
#define TT 2048
#define CC 768
#define NTOK (BB*TT)                     // 65536
#define NTOT 50331648LL                  // BB*TT*CC
#define RANK0 25165823ULL                // NTOT/2 - 1
#define RANK1 25165824ULL                // NTOT/2
#define CTH 0.0009765625f                // 2^-10
#define LBUF_CAP 512

typedef float nf4 __attribute__((ext_vector_type(4)));   // native vec for nontemporal

// ---- monotone float<->uint mapping (order-preserving) ----
__device__ inline unsigned int f2key(float f) {
    unsigned int u = __float_as_uint(f);
    return (u & 0x80000000u) ? ~u : (u | 0x80000000u);
}
__device__ inline float key2f(unsigned int k) {
    unsigned int u = (k & 0x80000000u) ? (k ^ 0x80000000u) : ~k;
    return __uint_as_float(u);
}

// ---- 1024-thread bucket select: NB bins, rank k -> res[0]=bin res[1]=prefix ----
template<int NB>
__device__ void sel1024(const unsigned int* __restrict__ hist,
                        unsigned long long k, unsigned int* res,
                        unsigned long long* pscan)
{
    const int t = threadIdx.x;
    constexpr int PER = NB / 1024;
    unsigned int loc[PER];
    unsigned long long lsum = 0;
    #pragma unroll
    for (int i = 0; i < PER; ++i) { loc[i] = hist[t * PER + i]; lsum += loc[i]; }
    pscan[t] = lsum;
    __syncthreads();
    for (int off = 1; off < 1024; off <<= 1) {
        unsigned long long v = (t >= off) ? pscan[t - off] : 0ULL;
        __syncthreads();
        pscan[t] += v;
        __syncthreads();
    }
    unsigned long long excl = (t == 0) ? 0ULL : pscan[t - 1];
    if (k >= excl && k < pscan[t]) {
        unsigned long long c = excl;
        #pragma unroll
        for (int i = 0; i < PER; ++i) {
            if (k < c + loc[i]) { res[0] = (unsigned int)(t * PER + i); res[1] = (unsigned int)c; break; }
            c += loc[i];
        }
    }
    __syncthreads();
}

__device__ inline void do_finstats(const unsigned int* scal, const double* g_sum,
                                   float* fscal)
{
    float v0 = key2f(scal[8]), v1 = key2f(scal[9]);
    float mean = __fmul_rn(__fadd_rn(v0, v1), 0.5f);
    double s = g_sum[0], ss = g_sum[1];
    const double NN = (double)NTOT;
    double var = (ss - s * s / NN) / (NN - 1.0);
    if (var < 0.0) var = 0.0;
    float stdf = (float)sqrt(var);
    float rng = __fsub_rn(fscal[4], fscal[3]);
    float coeff = __fdiv_rn(stdf, rng);
    fscal[0] = mean; fscal[1] = stdf; fscal[2] = coeff;
}

// ============ K1: wave-per-token stats + below-count + speculative compact ============
__global__ __launch_bounds__(256) void k_token_stats(
    const float4* __restrict__ x4, float* __restrict__ tokmin,
    float* __restrict__ tokmax, float* __restrict__ eulg,
    double* __restrict__ pS, double* __restrict__ pSS,
    float* __restrict__ pMn, float* __restrict__ pMx,
    unsigned int* __restrict__ cbuf, unsigned int* __restrict__ cnt,
    unsigned int* __restrict__ scal, unsigned int cap)
{
    __shared__ unsigned int lbuf[LBUF_CAP];
    __shared__ unsigned int lcnt, lbase;
    __shared__ double wS[4], wSS[4];
    __shared__ float wMn[4], wMx[4];
    __shared__ unsigned int wNlt[4];
    if (threadIdx.x == 0) lcnt = 0;
    __syncthreads();
    const int wave = threadIdx.x >> 6, lane = threadIdx.x & 63;

    double accS = 0.0, accSS = 0.0;
    float gmn = INFINITY, gmx = -INFINITY;
    unsigned int nlt = 0;

    for (int token = blockIdx.x * 4 + wave; token < NTOK; token += gridDim.x * 4) {
        const float4* xp = x4 + (size_t)token * 192;
        float mn = INFINITY, mx = -INFINITY;
        #pragma unroll
        for (int k = 0; k < 3; ++k) {
            float4 v = xp[lane + k * 64];
            #pragma unroll
            for (int c = 0; c < 4; ++c) {
                float vv = (c == 0) ? v.x : (c == 1) ? v.y : (c == 2) ? v.z : v.w;
                mn = fminf(mn, vv); mx = fmaxf(mx, vv);
                accS += (double)vv;
                accSS += (double)vv * (double)vv;
                nlt += (vv < -CTH) ? 1u : 0u;
                if (vv < CTH && vv >= -CTH) {
                    unsigned int p = atomicAdd(&lcnt, 1u);
                    if (p < LBUF_CAP) lbuf[p] = f2key(vv);
                }
            }
        }
        gmn = fminf(gmn, mn); gmx = fmaxf(gmx, mx);
        #pragma unroll
        for (int d = 1; d < 64; d <<= 1) {
            mn = fminf(mn, __shfl_xor(mn, d));
            mx = fmaxf(mx, __shfl_xor(mx, d));
        }
        if (lane == 0) {
            tokmin[token] = mn; tokmax[token] = mx;
            float e = __fsub_rn(mx, mn);
            if ((token & (TT - 1)) == 0) e = __fmul_rn(e, 1e8f);
            eulg[token] = e;
        }
    }
    #pragma unroll
    for (int d = 1; d < 64; d <<= 1) {
        accS  += __shfl_xor(accS, d);
        accSS += __shfl_xor(accSS, d);
        gmn = fminf(gmn, __shfl_xor(gmn, d));
        gmx = fmaxf(gmx, __shfl_xor(gmx, d));
        nlt += __shfl_xor(nlt, d);
    }
    if (lane == 0) { wS[wave] = accS; wSS[wave] = accSS; wMn[wave] = gmn;
                     wMx[wave] = gmx; wNlt[wave] = nlt; }
    __syncthreads();
    if (threadIdx.x == 0) {
        pS[blockIdx.x]  = wS[0] + wS[1] + wS[2] + wS[3];
        pSS[blockIdx.x] = wSS[0] + wSS[1] + wSS[2] + wSS[3];
        pMn[blockIdx.x] = fminf(fminf(wMn[0], wMn[1]), fminf(wMn[2], wMn[3]));
        pMx[blockIdx.x] = fmaxf(fmaxf(wMx[0], wMx[1]), fmaxf(wMx[2], wMx[3]));
        atomicAdd(&cnt[1], wNlt[0] + wNlt[1] + wNlt[2] + wNlt[3]);
        unsigned int n = lcnt;
        if (n > LBUF_CAP) { scal[10] = 1; n = LBUF_CAP; }
        unsigned int base = atomicAdd(&cnt[0], n);
        if (base + n > cap) scal[10] = 1;
        lbase = base; lcnt = n;
    }
    __syncthreads();
    {
        unsigned int n = lcnt, base = lbase;
        for (unsigned int i = threadIdx.x; i < n; i += 256) {
            unsigned int p = base + i;
            if (p < cap) cbuf[p] = lbuf[i];
        }
    }
}

// ============ K2: fused scalar kernel: reduce + median select + stats ============
__global__ __launch_bounds__(1024) void k_scalars(
    const double* __restrict__ pS, const double* __restrict__ pSS,
    const float* __restrict__ pMn, const float* __restrict__ pMx,
    const unsigned int* __restrict__ cnt, const unsigned int* __restrict__ cbuf,
    unsigned int cap, unsigned int* __restrict__ scal,
    double* __restrict__ g_sum, float* __restrict__ fscal)
{
    __shared__ double a[1024], b[1024];
    __shared__ float c[1024], d[1024];
    __shared__ unsigned int hist[2048];
    __shared__ unsigned long long pscan[1024];
    __shared__ unsigned int sres[2];
    __shared__ unsigned int sflag;
    const int t = threadIdx.x;

    a[t] = pS[t] + pS[t + 1024];
    b[t] = pSS[t] + pSS[t + 1024];
    c[t] = fminf(pMn[t], pMn[t + 1024]);
    d[t] = fmaxf(pMx[t], pMx[t + 1024]);
    __syncthreads();
    for (int st = 512; st > 0; st >>= 1) {
        if (t < st) {
            a[t] += a[t + st]; b[t] += b[t + st];
            c[t] = fminf(c[t], c[t + st]); d[t] = fmaxf(d[t], d[t + st]);
        }
        __syncthreads();
    }
    const unsigned int n = min(cnt[0], cap);
    const long long nlt = (long long)cnt[1];
    const long long r0 = (long long)RANK0 - nlt;
    const long long r1 = (long long)RANK1 - nlt;
    if (t == 0) {
        g_sum[0] = a[0]; g_sum[1] = b[0]; fscal[3] = c[0]; fscal[4] = d[0];
        unsigned int f = scal[10];
        if (r0 < 0 || r1 < 0 || r0 >= (long long)n || r1 >= (long long)n) f = 1;
        scal[10] = f; sflag = f;
    }
    __syncthreads();
    if (sflag) return;                               // fallback handles

    for (int r = 0; r < 2; ++r) {
        unsigned long long rin = (unsigned long long)(r ? r1 : r0);
        // level 1: top 11 bits
        for (int i = t; i < 2048; i += 1024) hist[i] = 0;
        __syncthreads();
        for (unsigned int i = t; i < n; i += 1024) atomicAdd(&hist[cbuf[i] >> 21], 1u);
        __syncthreads();
        sel1024<2048>(hist, rin, sres, pscan);
        unsigned int b1 = sres[0]; rin -= sres[1];
        __syncthreads();
        // level 2: mid 11 bits
        for (int i = t; i < 2048; i += 1024) hist[i] = 0;
        __syncthreads();
        for (unsigned int i = t; i < n; i += 1024) {
            unsigned int k2 = cbuf[i];
            if ((k2 >> 21) == b1) atomicAdd(&hist[(k2 >> 10) & 2047u], 1u);
        }
        __syncthreads();
        sel1024<2048>(hist, rin, sres, pscan);
        unsigned int b2 = sres[0]; rin -= sres[1];
        unsigned int top22 = (b1 << 11) | b2;
        __syncthreads();
        // level 3: low 10 bits
        for (int i = t; i < 1024; i += 1024) hist[i] = 0;
        __syncthreads();
        for (unsigned int i = t; i < n; i += 1024) {
            unsigned int k2 = cbuf[i];
            if ((k2 >> 10) == top22) atomicAdd(&hist[k2 & 1023u], 1u);
        }
        __syncthreads();
        sel1024<1024>(hist, rin, sres, pscan);
        if (t == 0) scal[8 + r] = (b1 << 21) | (b2 << 10) | sres[0];
        __syncthreads();
    }
    if (t == 0) do_finstats(scal, g_sum, fscal);
}

// ============ correctness fallback: exact 3-level select over all x (never taken) ============
__global__ __launch_bounds__(1024) void k_fallback(const float4* __restrict__ x4,
    unsigned int* __restrict__ scal, const double* __restrict__ g_sum,
    float* __restrict__ fscal)
{
    if (!scal[10]) return;                           // uniform
    __shared__ unsigned int h[2][2048];
    __shared__ unsigned long long pscan[1024];
    __shared__ unsigned int sres[2];
    __shared__ unsigned int sb1[2], sb2[2];
    __shared__ unsigned long long srank[2];
    const int t = threadIdx.x;
    const long long n4 = NTOT / 4;
    // level 1 (shared by both ranks)
    for (int i = t; i < 2048; i += 1024) h[0][i] = 0;
    __syncthreads();
    for (long long i = t; i < n4; i += 1024) {
        float4 v = x4[i];
        atomicAdd(&h[0][f2key(v.x) >> 21], 1u);
        atomicAdd(&h[0][f2key(v.y) >> 21], 1u);
        atomicAdd(&h[0][f2key(v.z) >> 21], 1u);
        atomicAdd(&h[0][f2key(v.w) >> 21], 1u);
    }
    __syncthreads();
    for (int r = 0; r < 2; ++r) {
        sel1024<2048>(h[0], r ? RANK1 : RANK0, sres, pscan);
        if (t == 0) { sb1[r] = sres[0]; srank[r] = (r ? RANK1 : RANK0) - sres[1]; }
        __syncthreads();
    }
    // level 2
    for (int i = t; i < 4096; i += 1024) ((unsigned int*)h)[i] = 0;
    __syncthreads();
    for (long long i = t; i < n4; i += 1024) {
        float4 v = x4[i];
        #pragma unroll
        for (int cc = 0; cc < 4; ++cc) {
            float f = (cc == 0) ? v.x : (cc == 1) ? v.y : (cc == 2) ? v.z : v.w;
            unsigned int k = f2key(f);
            unsigned int top = k >> 21, mid = (k >> 10) & 2047u;
            if (top == sb1[0]) atomicAdd(&h[0][mid], 1u);
            if (top == sb1[1]) atomicAdd(&h[1][mid], 1u);
        }
    }
    __syncthreads();
    for (int r = 0; r < 2; ++r) {
        sel1024<2048>(h[r], srank[r], sres, pscan);
        if (t == 0) { sb2[r] = sres[0]; srank[r] -= sres[1]; }
        __syncthreads();
    }
    // level 3
    for (int i = t; i < 4096; i += 1024) ((unsigned int*)h)[i] = 0;
    __syncthreads();
    for (long long i = t; i < n4; i += 1024) {
        float4 v = x4[i];
        #pragma unroll
        for (int cc = 0; cc < 4; ++cc) {
            float f = (cc == 0) ? v.x : (cc == 1) ? v.y : (cc == 2) ? v.z : v.w;
            unsigned int k = f2key(f);
            unsigned int t22 = k >> 10, low = k & 1023u;
            if (t22 == ((sb1[0] << 11) | sb2[0])) atomicAdd(&h[0][low], 1u);
            if (t22 == ((sb1[1] << 11) | sb2[1])) atomicAdd(&h[1][low], 1u);
        }
    }
    __syncthreads();
    for (int r = 0; r < 2; ++r) {
        sel1024<1024>(h[r], srank[r], sres, pscan);
        if (t == 0) scal[8 + r] = (sb1[r] << 21) | (sb2[r] << 10) | sres[0];
        __syncthreads();
    }
    if (t == 0) do_finstats(scal, g_sum, fscal);
}

// ============ K3: wave-per-token band counts -> attn_std ============
__global__ __launch_bounds__(256) void k_count(const float4* __restrict__ x4,
    const float* __restrict__ eulg, const float* __restrict__ fscal, float* __restrict__ attn)
{
    const int wave = threadIdx.x >> 6, lane = threadIdx.x & 63;
    const float mean = fscal[0], coeff = fscal[2];
    for (int token = blockIdx.x * 4 + wave; token < NTOK; token += gridDim.x * 4) {
        float band = __fmul_rn(__fmul_rn(eulg[token], coeff), 0.8f);
        float hi = __fadd_rn(mean, band);
        float lo = __fsub_rn(mean, band);
        const float4* xp = x4 + (size_t)token * 192;
        int d = 0;
        #pragma unroll
        for (int k = 0; k < 3; ++k) {
            float4 v = xp[lane + k * 64];
            d += (v.x < hi) - (v.x < lo) + (v.y < hi) - (v.y < lo)
               + (v.z < hi) - (v.z < lo) + (v.w < hi) - (v.w < lo);
        }
        #pragma unroll
        for (int s = 1; s < 64; s <<= 1) d += __shfl_xor(d, s);
        if (lane == 0) {
            float a = fmaxf((float)d, 76.8f);             // clip(.., COCO*C)
            float inv = __fdiv_rn(1.0f, a);
            attn[token] = (inv > 1.0f) ? 0.0f : inv;
        }
    }
}

// ============ K4: per-batch stable sort + score + binary-search desc ranks ============
__device__ inline void bitonic_sort(unsigned long long* keys, int tid, int nthr) {
    for (int k = 2; k <= TT; k <<= 1) {
        for (int j = k >> 1; j > 0; j >>= 1) {
            __syncthreads();
            for (int i = tid; i < TT; i += nthr) {
                int l = i ^ j;
                if (l > i) {
                    unsigned long long a = keys[i], c = keys[l];
                    bool up = ((i & k) == 0);
                    if (up ? (a > c) : (a < c)) { keys[i] = c; keys[l] = a; }
                }
            }
        }
    }
    __syncthreads();
}

__global__ __launch_bounds__(1024) void k_sort(const float* __restrict__ eulg,
    const float* __restrict__ attn, const float* __restrict__ fscal,
    unsigned int* __restrict__ nlev)
{
    int bb = blockIdx.x, tid = threadIdx.x;
    __shared__ unsigned long long keys[TT];
    __shared__ float av[TT];
    __shared__ int firstNeg;
    __shared__ int s_diff;
    const float stdf = fscal[1];
    const float THR = (float)(1.0 + 511.0 / 254.0);

    for (int t = tid; t < TT; t += 1024) {
        float v = eulg[bb * TT + t];
        keys[t] = ((unsigned long long)f2key(v) << 32) | (unsigned int)t;  // (value asc, idx asc)
    }
    if (tid == 0) firstNeg = TT;
    __syncthreads();
    bitonic_sort(keys, tid, 1024);

    for (int t = tid; t < TT; t += 1024)
        av[t] = attn[bb * TT + (unsigned int)(keys[t] & 0xffffffffu)];
    __syncthreads();

    for (int i = tid; i < TT; i += 1024) {
        float vi = key2f((unsigned int)(keys[i] >> 32));
        float vd = key2f((unsigned int)(keys[TT - 1 - i] >> 32));
        float a  = __fmul_rn(vd, av[TT - 1 - i]);
        float bt = __fmul_rn(__fmul_rn(vi, av[i]), THR);
        float sc = __fdiv_rn(__fsub_rn(a, bt), stdf);
        if (sc < 0.0f) atomicMin(&firstNeg, i);
    }
    __syncthreads();
    if (tid == 0) {
        int mi = (firstNeg >= TT) ? 0 : firstNeg;       // argmax(all False) = 0
        s_diff = (mi - 1 > 0) ? (mi - 1) : 0;
    }
    __syncthreads();
    int diffv = s_diff;

    // descending-stable rank via tie-group binary search:
    for (int i = tid; i < TT; i += 1024) {
        unsigned long long key = keys[i];
        unsigned int ku = (unsigned int)(key >> 32);
        unsigned long long tlo = ((unsigned long long)ku) << 32;
        int a = 0;
        for (int st = 1024; st > 0; st >>= 1) {
            int c = a + st;
            if (c <= TT && keys[c - 1] < tlo) a = c;
        }
        int b1;
        if (ku == 0xFFFFFFFFu) b1 = TT;
        else {
            unsigned long long thi = ((unsigned long long)(ku + 1)) << 32;
            b1 = 0;
            for (int st = 1024; st > 0; st >>= 1) {
                int c = b1 + st;
                if (c <= TT && keys[c - 1] < thi) b1 = c;
            }
        }
        int rank = TT - b1 + i - a;
        unsigned int token = (unsigned int)(key & 0xffffffffu);
        unsigned int levels = (rank > TT - 2 - diffv) ? 128u
                            : ((rank <= diffv) ? 512u : 256u);
        nlev[bb * TT + token] = levels;
    }
}

// ============ K5: wave-per-token quantize / dequantize (nt stores) ============
__global__ __launch_bounds__(256) void k_quant(const float4* __restrict__ x4,
    const float* __restrict__ tokmin, const float* __restrict__ tokmax,
    const unsigned int* __restrict__ nlev, float4* __restrict__ out)
{
    const int wave = threadIdx.x >> 6, lane = threadIdx.x & 63;
    for (int token = blockIdx.x * 4 + wave; token < NTOK; token += gridDim.x * 4) {
        float mn = tokmin[token], mx = tokmax[token];
        float delta = fmaxf(__fdiv_rn(__fsub_rn(mx, mn), 255.0f), 1e-8f);
        float zp = rintf(__fdiv_rn(-mn, delta));
        float nlm1 = (float)(nlev[token] - 1u);
        const float4* xp = x4 + (size_t)token * 192;
        nf4* op = (nf4*)(out + (size_t)token * 192);
        #pragma unroll
        for (int k = 0; k < 3; ++k) {
            float4 v = xp[lane + k * 64];
            nf4 r;
            #pragma unroll
            for (int c = 0; c < 4; ++c) {
                float vv = (c == 0) ? v.x : (c == 1) ? v.y : (c == 2) ? v.z : v.w;
                float xi = __fadd_rn(rintf(__fdiv_rn(vv, delta)), zp);
                float t = __fdiv_rn(xi, nlm1);
                t = fminf(fmaxf(t, 0.0f), 1.0f);
                float xq = __fmul_rn(t, nlm1);
                r[c] = __fmul_rn(__fsub_rn(xq, zp), delta);
            }
            __builtin_nontemporal_store(r, &op[lane + k * 64]);
        }
    }
}

extern "C" void kernel_launch(void* const* d_in, const int* in_sizes, int n_in,
                              void* d_out, int out_size, void* d_ws, size_t ws_size,
                              hipStream_t stream)
{
    (void)in_sizes; (void)n_in; (void)out_size;
    const float* x = (const float*)d_in[0];
    float* out = (float*)d_out;
    char* ws = (char*)d_ws;

    double* g_sum = (double*)ws;                           // [0]=sum [1]=sumsq
    unsigned int* scal = (unsigned int*)(ws + 16);         // [8..9]=keys [10]=flag
    unsigned int* cnt = (unsigned int*)(ws + 64);          // [0]=cbuf n [1]=nlt
    float* fscal = (float*)(ws + 96);                      // mean,std,coeff,gmin,gmax
    float* tokmin = (float*)(ws + 16384);
    float* tokmax = tokmin + NTOK;
    float* eulg   = tokmax + NTOK;
    float* attn   = eulg + NTOK;
    unsigned int* nlev = (unsigned int*)(attn + NTOK);     // ends 1327104
    double* pS  = (double*)(ws + 1327104);                 // 2048 doubles
    double* pSS = pS + 2048;
    float* pMn  = (float*)(pSS + 2048);                    // 2048 floats
    float* pMx  = pMn + 2048;                              // ends 1376256
    unsigned int* cbuf = (unsigned int*)(ws + 1376256);
    unsigned int cap = 0;
    if (ws_size > 1376256 + 4096)
        cap = (unsigned int)min((size_t)(1u << 20), (ws_size - 1376256) / 4);

    (void)hipMemsetAsync(ws, 0, 128, stream);              // g_sum + scal + cnt

    k_token_stats<<<2048, 256, 0, stream>>>((const float4*)x, tokmin, tokmax, eulg,
                                            pS, pSS, pMn, pMx, cbuf, cnt, scal, cap);
    k_scalars<<<1, 1024, 0, stream>>>(pS, pSS, pMn, pMx, cnt, cbuf, cap,
                                      scal, g_sum, fscal);
    k_fallback<<<1, 1024, 0, stream>>>((const float4*)x, scal, g_sum, fscal);
    k_count<<<2048, 256, 0, stream>>>((const float4*)x, eulg, fscal, attn);
    k_sort<<<BB, 1024, 0, stream>>>(eulg, attn, fscal, nlev);
    k_quant<<<2048, 256, 0, stream>>>((const float4*)x, tokmin, tokmax, nlev, (float4*)out);
}